// Round 1
// baseline (458.261 us; speedup 1.0000x reference)
//
#include <hip/hip_runtime.h>
#include <math.h>

#define RRELU_SLOPE 0.22916667f  // (1/8 + 1/3)/2 = 11/48

// ---------------------------------------------------------------------------
// CSR build: histogram -> scan -> scatter
// ---------------------------------------------------------------------------

__global__ __launch_bounds__(256) void k_deg(const int* __restrict__ dst, int E,
                                             int* __restrict__ cnt) {
    int e = blockIdx.x * 256 + threadIdx.x;
    if (e < E) atomicAdd(&cnt[dst[e]], 1);
}

// per-block sums of cnt
__global__ __launch_bounds__(256) void k_scan1(const int* __restrict__ cnt, int N,
                                               int* __restrict__ bsum) {
    int i = blockIdx.x * 256 + threadIdx.x;
    int v = (i < N) ? cnt[i] : 0;
    for (int o = 32; o >= 1; o >>= 1) v += __shfl_xor(v, o, 64);
    __shared__ int ws[4];
    if ((threadIdx.x & 63) == 0) ws[threadIdx.x >> 6] = v;
    __syncthreads();
    if (threadIdx.x == 0) bsum[blockIdx.x] = ws[0] + ws[1] + ws[2] + ws[3];
}

// exclusive scan of up to 1024 block sums (single block, 256 threads x 4)
__global__ __launch_bounds__(256) void k_scan2(const int* __restrict__ bsum, int NB,
                                               int* __restrict__ boff,
                                               int* __restrict__ rowp, int N, int E) {
    __shared__ int s[256];
    int t = threadIdx.x;
    int v[4];
    int loc = 0;
    for (int i = 0; i < 4; i++) {
        int idx = t * 4 + i;
        v[i] = (idx < NB) ? bsum[idx] : 0;
        loc += v[i];
    }
    s[t] = loc;
    __syncthreads();
    for (int o = 1; o < 256; o <<= 1) {
        int u = (t >= o) ? s[t - o] : 0;
        __syncthreads();
        s[t] += u;
        __syncthreads();
    }
    int excl = s[t] - loc;
    for (int i = 0; i < 4; i++) {
        int idx = t * 4 + i;
        if (idx < NB) { boff[idx] = excl; excl += v[i]; }
    }
    if (t == 0) rowp[N] = E;
}

// per-element exclusive scan + dinv
__global__ __launch_bounds__(256) void k_scan3(const int* __restrict__ cnt,
                                               const int* __restrict__ boff, int N,
                                               int* __restrict__ rowp,
                                               int* __restrict__ nxt,
                                               float* __restrict__ dinv) {
    int i = blockIdx.x * 256 + threadIdx.x;
    int lane = threadIdx.x & 63, wid = threadIdx.x >> 6;
    int v = (i < N) ? cnt[i] : 0;
    int inc = v;
    for (int o = 1; o < 64; o <<= 1) {
        int u = __shfl_up(inc, o, 64);
        if (lane >= o) inc += u;
    }
    __shared__ int wsum[4];
    if (lane == 63) wsum[wid] = inc;
    __syncthreads();
    int wo = 0;
    for (int w = 0; w < wid; w++) wo += wsum[w];
    if (i < N) {
        int excl = inc - v + wo + boff[blockIdx.x];
        rowp[i] = excl;
        nxt[i] = excl;
        dinv[i] = 1.0f / sqrtf((float)v + 1.0f);
    }
}

// scatter edges into CSR slots; pack (src, norm) as int2
__global__ __launch_bounds__(256) void k_fill(const int* __restrict__ src,
                                              const int* __restrict__ dst, int E,
                                              int* __restrict__ nxt,
                                              const float* __restrict__ dinv,
                                              int2* __restrict__ pair) {
    int e = blockIdx.x * 256 + threadIdx.x;
    if (e >= E) return;
    int s = src[e], d = dst[e];
    int p = atomicAdd(&nxt[d], 1);
    float v = dinv[s] * dinv[d];
    pair[p] = make_int2(s, __float_as_int(v));
}

// ---------------------------------------------------------------------------
// Dense matmul: H = A[N,K] @ W[K,64]. blockIdx.y selects (A0,W0,H0)/(A1,W1,H1).
// 4 waves/block, 4 rows/wave. W cached in LDS (layout [k][j], 2-way free).
// ---------------------------------------------------------------------------
template <int K>
__global__ __launch_bounds__(256) void k_mm2(const float* __restrict__ A0,
                                             const float* __restrict__ W0,
                                             float* __restrict__ H0,
                                             const float* __restrict__ A1,
                                             const float* __restrict__ W1,
                                             float* __restrict__ H1, int N) {
    const float* A = blockIdx.y ? A1 : A0;
    const float* W = blockIdx.y ? W1 : W0;
    float* H = blockIdx.y ? H1 : H0;
    __shared__ float Wl[K * 64];
    for (int idx = threadIdx.x; idx < K * 16; idx += 256)
        ((float4*)Wl)[idx] = ((const float4*)W)[idx];
    __syncthreads();
    int wid = threadIdx.x >> 6, lane = threadIdx.x & 63;
    long row0 = ((long)blockIdx.x * 4 + wid) * 4;
    if (row0 >= N) return;
    if (row0 + 3 < N) {
        const float* a0 = A + row0 * K;
        const float* a1 = a0 + K;
        const float* a2 = a0 + 2 * K;
        const float* a3 = a0 + 3 * K;
        float c0 = 0, c1 = 0, c2 = 0, c3 = 0;
        for (int k = 0; k < K; k += 4) {
            float4 v0 = *(const float4*)(a0 + k);
            float4 v1 = *(const float4*)(a1 + k);
            float4 v2 = *(const float4*)(a2 + k);
            float4 v3 = *(const float4*)(a3 + k);
#pragma unroll
            for (int kk = 0; kk < 4; kk++) {
                float w = Wl[(k + kk) * 64 + lane];
                c0 = fmaf(((const float*)&v0)[kk], w, c0);
                c1 = fmaf(((const float*)&v1)[kk], w, c1);
                c2 = fmaf(((const float*)&v2)[kk], w, c2);
                c3 = fmaf(((const float*)&v3)[kk], w, c3);
            }
        }
        H[row0 * 64 + lane] = c0;
        H[(row0 + 1) * 64 + lane] = c1;
        H[(row0 + 2) * 64 + lane] = c2;
        H[(row0 + 3) * 64 + lane] = c3;
    } else {
        for (long r = row0; r < N; r++) {
            float c = 0;
            for (int k = 0; k < K; k++) c = fmaf(A[r * K + k], Wl[k * 64 + lane], c);
            H[r * 64 + lane] = c;
        }
    }
}

// ---------------------------------------------------------------------------
// Fused aggregation for both branches + bias + rrelu. One wave per node,
// lane = feature.
// ---------------------------------------------------------------------------
__global__ __launch_bounds__(256) void k_agg_act(
    const int* __restrict__ rowp, const int2* __restrict__ pair,
    const float* __restrict__ dinv, const float* __restrict__ Hz,
    const float* __restrict__ Hx, const float* __restrict__ bz,
    const float* __restrict__ bx, float* __restrict__ Az, float* __restrict__ Ax,
    int N) {
    int wid = threadIdx.x >> 6, lane = threadIdx.x & 63;
    int i = blockIdx.x * 4 + wid;
    if (i >= N) return;
    int beg = rowp[i], end = rowp[i + 1];
    float sz = 0.f, sx = 0.f;
    for (int p = beg; p < end; p++) {
        int2 cv = pair[p];
        int c = cv.x;
        float v = __int_as_float(cv.y);
        sz = fmaf(v, Hz[(size_t)c * 64 + lane], sz);
        sx = fmaf(v, Hx[(size_t)c * 64 + lane], sx);
    }
    float dv = dinv[i];
    float sw = dv * dv;
    sz = fmaf(sw, Hz[(size_t)i * 64 + lane], sz) + bz[lane];
    sx = fmaf(sw, Hx[(size_t)i * 64 + lane], sx) + bx[lane];
    sz = sz >= 0.f ? sz : sz * RRELU_SLOPE;
    sx = sx >= 0.f ? sx : sx * RRELU_SLOPE;
    Az[(size_t)i * 64 + lane] = sz;
    Ax[(size_t)i * 64 + lane] = sx;
}

// Final layer: aggregation + bias + tanh (both branches) + product + W_out dot.
__global__ __launch_bounds__(256) void k_agg_final(
    const int* __restrict__ rowp, const int2* __restrict__ pair,
    const float* __restrict__ dinv, const float* __restrict__ Hz,
    const float* __restrict__ Hx, const float* __restrict__ bz,
    const float* __restrict__ bx, const float* __restrict__ Wout,
    const float* __restrict__ bout, float* __restrict__ out, int N) {
    int wid = threadIdx.x >> 6, lane = threadIdx.x & 63;
    int i = blockIdx.x * 4 + wid;
    if (i >= N) return;
    int beg = rowp[i], end = rowp[i + 1];
    float sz = 0.f, sx = 0.f;
    for (int p = beg; p < end; p++) {
        int2 cv = pair[p];
        int c = cv.x;
        float v = __int_as_float(cv.y);
        sz = fmaf(v, Hz[(size_t)c * 64 + lane], sz);
        sx = fmaf(v, Hx[(size_t)c * 64 + lane], sx);
    }
    float dv = dinv[i];
    float sw = dv * dv;
    sz = fmaf(sw, Hz[(size_t)i * 64 + lane], sz) + bz[lane];
    sx = fmaf(sw, Hx[(size_t)i * 64 + lane], sx) + bx[lane];
    float prod = tanhf(sz) * tanhf(sx) * Wout[lane];
    for (int o = 32; o >= 1; o >>= 1) prod += __shfl_xor(prod, o, 64);
    if (lane == 0) out[i] = prod + bout[0];
}

// ---------------------------------------------------------------------------

extern "C" void kernel_launch(void* const* d_in, const int* in_sizes, int n_in,
                              void* d_out, int out_size, void* d_ws, size_t ws_size,
                              hipStream_t stream) {
    const float* z = (const float*)d_in[0];
    const float* x = (const float*)d_in[1];
    const int* ei = (const int*)d_in[2];
    const float* We1 = (const float*)d_in[3];
    const float* be1 = (const float*)d_in[4];
    const float* We2 = (const float*)d_in[5];
    const float* be2 = (const float*)d_in[6];
    const float* Wf1 = (const float*)d_in[7];
    const float* bf1 = (const float*)d_in[8];
    const float* Wf2 = (const float*)d_in[9];
    const float* bf2 = (const float*)d_in[10];
    const float* Wout = (const float*)d_in[11];
    const float* bout = (const float*)d_in[12];
    float* out = (float*)d_out;

    int N = in_sizes[0] / 128;
    int E = in_sizes[2] / 2;
    const int* src = ei;
    const int* dst = ei + E;

    char* base = (char*)d_ws;
    size_t off = 0;
    auto take = [&](size_t nbytes) -> char* {
        char* p = base + off;
        off = (off + nbytes + 255) & ~(size_t)255;
        return p;
    };
    int NB = (N + 255) / 256;
    int* cnt = (int*)take((size_t)N * 4);
    int* bsum = (int*)take(1024 * 4);
    int* boff = (int*)take(1024 * 4);
    int* rowp = (int*)take(((size_t)N + 1) * 4);
    int* nxt = (int*)take((size_t)N * 4);
    float* dinv = (float*)take((size_t)N * 4);
    int2* pair = (int2*)take((size_t)E * 8);
    float* hz = (float*)take((size_t)N * 64 * 4);
    float* hx = (float*)take((size_t)N * 64 * 4);
    float* az = (float*)take((size_t)N * 64 * 4);
    float* ax = (float*)take((size_t)N * 64 * 4);

    hipMemsetAsync(cnt, 0, (size_t)N * 4, stream);

    int egrid = (E + 255) / 256;
    k_deg<<<egrid, 256, 0, stream>>>(dst, E, cnt);
    k_scan1<<<NB, 256, 0, stream>>>(cnt, N, bsum);
    k_scan2<<<1, 256, 0, stream>>>(bsum, NB, boff, rowp, N, E);
    k_scan3<<<NB, 256, 0, stream>>>(cnt, boff, N, rowp, nxt, dinv);
    k_fill<<<egrid, 256, 0, stream>>>(src, dst, E, nxt, dinv, pair);

    dim3 mmgrid((N + 15) / 16, 2);
    int agrid = (N + 3) / 4;

    // layer 1: hz = z@We1, hx = x@Wf1 ; agg + rrelu -> az, ax
    k_mm2<128><<<mmgrid, 256, 0, stream>>>(z, We1, hz, x, Wf1, hx, N);
    k_agg_act<<<agrid, 256, 0, stream>>>(rowp, pair, dinv, hz, hx, be1, bf1, az, ax, N);
    // layer 2: hz = az@We2, hx = ax@Wf2 ; agg + tanh + product + out
    k_mm2<64><<<mmgrid, 256, 0, stream>>>(az, We2, hz, ax, Wf2, hx, N);
    k_agg_final<<<agrid, 256, 0, stream>>>(rowp, pair, dinv, hz, hx, be2, bf2, Wout,
                                           bout, out, N);
}

// Round 2
// 323.333 us; speedup vs baseline: 1.4173x; 1.4173x over previous
//
#include <hip/hip_runtime.h>
#include <math.h>

#define RRELU_SLOPE 0.22916667f  // (1/8 + 1/3)/2 = 11/48

// ---------------------------------------------------------------------------
// CSR build: histogram -> scan -> scatter
// ---------------------------------------------------------------------------

__global__ __launch_bounds__(256) void k_deg(const int* __restrict__ dst, int E,
                                             int* __restrict__ cnt) {
    int e = blockIdx.x * 256 + threadIdx.x;
    if (e < E) atomicAdd(&cnt[dst[e]], 1);
}

// per-block sums of cnt
__global__ __launch_bounds__(256) void k_scan1(const int* __restrict__ cnt, int N,
                                               int* __restrict__ bsum) {
    int i = blockIdx.x * 256 + threadIdx.x;
    int v = (i < N) ? cnt[i] : 0;
    for (int o = 32; o >= 1; o >>= 1) v += __shfl_xor(v, o, 64);
    __shared__ int ws[4];
    if ((threadIdx.x & 63) == 0) ws[threadIdx.x >> 6] = v;
    __syncthreads();
    if (threadIdx.x == 0) bsum[blockIdx.x] = ws[0] + ws[1] + ws[2] + ws[3];
}

// exclusive scan of up to 1024 block sums (single block, 256 threads x 4)
__global__ __launch_bounds__(256) void k_scan2(const int* __restrict__ bsum, int NB,
                                               int* __restrict__ boff,
                                               int* __restrict__ rowp, int N, int E) {
    __shared__ int s[256];
    int t = threadIdx.x;
    int v[4];
    int loc = 0;
    for (int i = 0; i < 4; i++) {
        int idx = t * 4 + i;
        v[i] = (idx < NB) ? bsum[idx] : 0;
        loc += v[i];
    }
    s[t] = loc;
    __syncthreads();
    for (int o = 1; o < 256; o <<= 1) {
        int u = (t >= o) ? s[t - o] : 0;
        __syncthreads();
        s[t] += u;
        __syncthreads();
    }
    int excl = s[t] - loc;
    for (int i = 0; i < 4; i++) {
        int idx = t * 4 + i;
        if (idx < NB) { boff[idx] = excl; excl += v[i]; }
    }
    if (t == 0) rowp[N] = E;
}

// per-element exclusive scan + dinv
__global__ __launch_bounds__(256) void k_scan3(const int* __restrict__ cnt,
                                               const int* __restrict__ boff, int N,
                                               int* __restrict__ rowp,
                                               int* __restrict__ nxt,
                                               float* __restrict__ dinv) {
    int i = blockIdx.x * 256 + threadIdx.x;
    int lane = threadIdx.x & 63, wid = threadIdx.x >> 6;
    int v = (i < N) ? cnt[i] : 0;
    int inc = v;
    for (int o = 1; o < 64; o <<= 1) {
        int u = __shfl_up(inc, o, 64);
        if (lane >= o) inc += u;
    }
    __shared__ int wsum[4];
    if (lane == 63) wsum[wid] = inc;
    __syncthreads();
    int wo = 0;
    for (int w = 0; w < wid; w++) wo += wsum[w];
    if (i < N) {
        int excl = inc - v + wo + boff[blockIdx.x];
        rowp[i] = excl;
        nxt[i] = excl;
        dinv[i] = 1.0f / sqrtf((float)v + 1.0f);
    }
}

// scatter edges into CSR slots; pack (src, norm) as int2
__global__ __launch_bounds__(256) void k_fill(const int* __restrict__ src,
                                              const int* __restrict__ dst, int E,
                                              int* __restrict__ nxt,
                                              const float* __restrict__ dinv,
                                              int2* __restrict__ pair) {
    int e = blockIdx.x * 256 + threadIdx.x;
    if (e >= E) return;
    int s = src[e], d = dst[e];
    int p = atomicAdd(&nxt[d], 1);
    float v = dinv[s] * dinv[d];
    pair[p] = make_int2(s, __float_as_int(v));
}

// ---------------------------------------------------------------------------
// Dense matmul v2: H = A[N,K] @ W[K,64], LDS-tiled, 4x4 register micro-kernel.
// Block = 256 threads (16x16 thread grid) -> 64x64 output tile.
// blockIdx.y selects branch (A0,W0,H0)/(A1,W1,H1).
// ---------------------------------------------------------------------------
template <int K>
__global__ __launch_bounds__(256) void k_mm_tile(
    const float* __restrict__ A0, const float* __restrict__ W0,
    float* __restrict__ H0, const float* __restrict__ A1,
    const float* __restrict__ W1, float* __restrict__ H1, int N) {
    const float* A = blockIdx.y ? A1 : A0;
    const float* W = blockIdx.y ? W1 : W0;
    float* H = blockIdx.y ? H1 : H0;

    __shared__ float As[64][20];  // 64 rows x 16 k (stride 20 = 80B, 16B-aligned)
    __shared__ float Ws[16][64];  // 16 k x 64 cols

    const int tid = threadIdx.x;
    const int tc = tid & 15;   // output col group (4 cols)
    const int tr = tid >> 4;   // output row group (4 rows)
    const int row0 = blockIdx.x * 64;

    // staging assignments
    const int srow = tid >> 2;        // 0..63 : A row within tile
    const int sk = (tid & 3) * 4;     // 0,4,8,12 : k offset
    const int wk = tid >> 4;          // 0..15 : W k-row
    const int wc = (tid & 15) * 4;    // 0..60 : W col offset

    float acc[4][4] = {};

    for (int k0 = 0; k0 < K; k0 += 16) {
        // global loads (before barrier so they overlap previous compute)
        float4 av = make_float4(0.f, 0.f, 0.f, 0.f);
        int gr = row0 + srow;
        if (gr < N) av = *(const float4*)(A + (size_t)gr * K + k0 + sk);
        float4 wv = *(const float4*)(W + (size_t)(k0 + wk) * 64 + wc);
        __syncthreads();  // previous iter's LDS reads done
        *(float4*)&As[srow][sk] = av;
        *(float4*)&Ws[wk][wc] = wv;
        __syncthreads();

#pragma unroll
        for (int k = 0; k < 16; k += 4) {
            float4 a4[4], w4[4];
#pragma unroll
            for (int i = 0; i < 4; i++) a4[i] = *(const float4*)&As[tr * 4 + i][k];
#pragma unroll
            for (int kk = 0; kk < 4; kk++) w4[kk] = *(const float4*)&Ws[k + kk][tc * 4];
#pragma unroll
            for (int i = 0; i < 4; i++) {
                const float* ap = (const float*)&a4[i];
#pragma unroll
                for (int kk = 0; kk < 4; kk++) {
                    const float* wp = (const float*)&w4[kk];
                    float a = ap[kk];
                    acc[i][0] = fmaf(a, wp[0], acc[i][0]);
                    acc[i][1] = fmaf(a, wp[1], acc[i][1]);
                    acc[i][2] = fmaf(a, wp[2], acc[i][2]);
                    acc[i][3] = fmaf(a, wp[3], acc[i][3]);
                }
            }
        }
    }

#pragma unroll
    for (int i = 0; i < 4; i++) {
        int r = row0 + tr * 4 + i;
        if (r < N) {
            *(float4*)(H + (size_t)r * 64 + tc * 4) =
                make_float4(acc[i][0], acc[i][1], acc[i][2], acc[i][3]);
        }
    }
}

// ---------------------------------------------------------------------------
// Fused aggregation for both branches + bias + rrelu. One wave per node,
// lane = feature.
// ---------------------------------------------------------------------------
__global__ __launch_bounds__(256) void k_agg_act(
    const int* __restrict__ rowp, const int2* __restrict__ pair,
    const float* __restrict__ dinv, const float* __restrict__ Hz,
    const float* __restrict__ Hx, const float* __restrict__ bz,
    const float* __restrict__ bx, float* __restrict__ Az, float* __restrict__ Ax,
    int N) {
    int wid = threadIdx.x >> 6, lane = threadIdx.x & 63;
    int i = blockIdx.x * 4 + wid;
    if (i >= N) return;
    int beg = rowp[i], end = rowp[i + 1];
    float sz = 0.f, sx = 0.f;
    for (int p = beg; p < end; p++) {
        int2 cv = pair[p];
        int c = cv.x;
        float v = __int_as_float(cv.y);
        sz = fmaf(v, Hz[(size_t)c * 64 + lane], sz);
        sx = fmaf(v, Hx[(size_t)c * 64 + lane], sx);
    }
    float dv = dinv[i];
    float sw = dv * dv;
    sz = fmaf(sw, Hz[(size_t)i * 64 + lane], sz) + bz[lane];
    sx = fmaf(sw, Hx[(size_t)i * 64 + lane], sx) + bx[lane];
    sz = sz >= 0.f ? sz : sz * RRELU_SLOPE;
    sx = sx >= 0.f ? sx : sx * RRELU_SLOPE;
    Az[(size_t)i * 64 + lane] = sz;
    Ax[(size_t)i * 64 + lane] = sx;
}

// Final layer: aggregation + bias + tanh (both branches) + product + W_out dot.
__global__ __launch_bounds__(256) void k_agg_final(
    const int* __restrict__ rowp, const int2* __restrict__ pair,
    const float* __restrict__ dinv, const float* __restrict__ Hz,
    const float* __restrict__ Hx, const float* __restrict__ bz,
    const float* __restrict__ bx, const float* __restrict__ Wout,
    const float* __restrict__ bout, float* __restrict__ out, int N) {
    int wid = threadIdx.x >> 6, lane = threadIdx.x & 63;
    int i = blockIdx.x * 4 + wid;
    if (i >= N) return;
    int beg = rowp[i], end = rowp[i + 1];
    float sz = 0.f, sx = 0.f;
    for (int p = beg; p < end; p++) {
        int2 cv = pair[p];
        int c = cv.x;
        float v = __int_as_float(cv.y);
        sz = fmaf(v, Hz[(size_t)c * 64 + lane], sz);
        sx = fmaf(v, Hx[(size_t)c * 64 + lane], sx);
    }
    float dv = dinv[i];
    float sw = dv * dv;
    sz = fmaf(sw, Hz[(size_t)i * 64 + lane], sz) + bz[lane];
    sx = fmaf(sw, Hx[(size_t)i * 64 + lane], sx) + bx[lane];
    float prod = tanhf(sz) * tanhf(sx) * Wout[lane];
    for (int o = 32; o >= 1; o >>= 1) prod += __shfl_xor(prod, o, 64);
    if (lane == 0) out[i] = prod + bout[0];
}

// ---------------------------------------------------------------------------

extern "C" void kernel_launch(void* const* d_in, const int* in_sizes, int n_in,
                              void* d_out, int out_size, void* d_ws, size_t ws_size,
                              hipStream_t stream) {
    const float* z = (const float*)d_in[0];
    const float* x = (const float*)d_in[1];
    const int* ei = (const int*)d_in[2];
    const float* We1 = (const float*)d_in[3];
    const float* be1 = (const float*)d_in[4];
    const float* We2 = (const float*)d_in[5];
    const float* be2 = (const float*)d_in[6];
    const float* Wf1 = (const float*)d_in[7];
    const float* bf1 = (const float*)d_in[8];
    const float* Wf2 = (const float*)d_in[9];
    const float* bf2 = (const float*)d_in[10];
    const float* Wout = (const float*)d_in[11];
    const float* bout = (const float*)d_in[12];
    float* out = (float*)d_out;

    int N = in_sizes[0] / 128;
    int E = in_sizes[2] / 2;
    const int* src = ei;
    const int* dst = ei + E;

    char* base = (char*)d_ws;
    size_t off = 0;
    auto take = [&](size_t nbytes) -> char* {
        char* p = base + off;
        off = (off + nbytes + 255) & ~(size_t)255;
        return p;
    };
    int NB = (N + 255) / 256;
    int* cnt = (int*)take((size_t)N * 4);
    int* bsum = (int*)take(1024 * 4);
    int* boff = (int*)take(1024 * 4);
    int* rowp = (int*)take(((size_t)N + 1) * 4);
    int* nxt = (int*)take((size_t)N * 4);
    float* dinv = (float*)take((size_t)N * 4);
    int2* pair = (int2*)take((size_t)E * 8);
    float* hz = (float*)take((size_t)N * 64 * 4);
    float* hx = (float*)take((size_t)N * 64 * 4);
    float* az = (float*)take((size_t)N * 64 * 4);
    float* ax = (float*)take((size_t)N * 64 * 4);

    hipMemsetAsync(cnt, 0, (size_t)N * 4, stream);

    int egrid = (E + 255) / 256;
    k_deg<<<egrid, 256, 0, stream>>>(dst, E, cnt);
    k_scan1<<<NB, 256, 0, stream>>>(cnt, N, bsum);
    k_scan2<<<1, 256, 0, stream>>>(bsum, NB, boff, rowp, N, E);
    k_scan3<<<NB, 256, 0, stream>>>(cnt, boff, N, rowp, nxt, dinv);
    k_fill<<<egrid, 256, 0, stream>>>(src, dst, E, nxt, dinv, pair);

    dim3 mmgrid((N + 63) / 64, 2);
    int agrid = (N + 3) / 4;

    // layer 1: hz = z@We1, hx = x@Wf1 ; agg + rrelu -> az, ax
    k_mm_tile<128><<<mmgrid, 256, 0, stream>>>(z, We1, hz, x, Wf1, hx, N);
    k_agg_act<<<agrid, 256, 0, stream>>>(rowp, pair, dinv, hz, hx, be1, bf1, az, ax, N);
    // layer 2: hz = az@We2, hx = ax@Wf2 ; agg + tanh + product + out
    k_mm_tile<64><<<mmgrid, 256, 0, stream>>>(az, We2, hz, ax, Wf2, hx, N);
    k_agg_final<<<agrid, 256, 0, stream>>>(rowp, pair, dinv, hz, hx, be2, bf2, Wout,
                                           bout, out, N);
}

// Round 3
// 281.672 us; speedup vs baseline: 1.6269x; 1.1479x over previous
//
#include <hip/hip_runtime.h>
#include <math.h>

#define RRELU_SLOPE 0.22916667f  // (1/8 + 1/3)/2 = 11/48

// ---------------------------------------------------------------------------
// CSR build: histogram -> scan -> scatter
// ---------------------------------------------------------------------------

__global__ __launch_bounds__(256) void k_deg(const int* __restrict__ dst, int E,
                                             int* __restrict__ cnt) {
    int e = blockIdx.x * 256 + threadIdx.x;
    if (e < E) atomicAdd(&cnt[dst[e]], 1);
}

__global__ __launch_bounds__(256) void k_scan1(const int* __restrict__ cnt, int N,
                                               int* __restrict__ bsum) {
    int i = blockIdx.x * 256 + threadIdx.x;
    int v = (i < N) ? cnt[i] : 0;
    for (int o = 32; o >= 1; o >>= 1) v += __shfl_xor(v, o, 64);
    __shared__ int ws[4];
    if ((threadIdx.x & 63) == 0) ws[threadIdx.x >> 6] = v;
    __syncthreads();
    if (threadIdx.x == 0) bsum[blockIdx.x] = ws[0] + ws[1] + ws[2] + ws[3];
}

__global__ __launch_bounds__(256) void k_scan2(const int* __restrict__ bsum, int NB,
                                               int* __restrict__ boff,
                                               int* __restrict__ rowp, int N, int E) {
    __shared__ int s[256];
    int t = threadIdx.x;
    int v[4];
    int loc = 0;
    for (int i = 0; i < 4; i++) {
        int idx = t * 4 + i;
        v[i] = (idx < NB) ? bsum[idx] : 0;
        loc += v[i];
    }
    s[t] = loc;
    __syncthreads();
    for (int o = 1; o < 256; o <<= 1) {
        int u = (t >= o) ? s[t - o] : 0;
        __syncthreads();
        s[t] += u;
        __syncthreads();
    }
    int excl = s[t] - loc;
    for (int i = 0; i < 4; i++) {
        int idx = t * 4 + i;
        if (idx < NB) { boff[idx] = excl; excl += v[i]; }
    }
    if (t == 0) rowp[N] = E;
}

__global__ __launch_bounds__(256) void k_scan3(const int* __restrict__ cnt,
                                               const int* __restrict__ boff, int N,
                                               int* __restrict__ rowp,
                                               int* __restrict__ nxt,
                                               float* __restrict__ dinv) {
    int i = blockIdx.x * 256 + threadIdx.x;
    int lane = threadIdx.x & 63, wid = threadIdx.x >> 6;
    int v = (i < N) ? cnt[i] : 0;
    int inc = v;
    for (int o = 1; o < 64; o <<= 1) {
        int u = __shfl_up(inc, o, 64);
        if (lane >= o) inc += u;
    }
    __shared__ int wsum[4];
    if (lane == 63) wsum[wid] = inc;
    __syncthreads();
    int wo = 0;
    for (int w = 0; w < wid; w++) wo += wsum[w];
    if (i < N) {
        int excl = inc - v + wo + boff[blockIdx.x];
        rowp[i] = excl;
        nxt[i] = excl;
        dinv[i] = 1.0f / sqrtf((float)v + 1.0f);
    }
}

__global__ __launch_bounds__(256) void k_fill(const int* __restrict__ src,
                                              const int* __restrict__ dst, int E,
                                              int* __restrict__ nxt,
                                              const float* __restrict__ dinv,
                                              int2* __restrict__ pair) {
    int e = blockIdx.x * 256 + threadIdx.x;
    if (e >= E) return;
    int s = src[e], d = dst[e];
    int p = atomicAdd(&nxt[d], 1);
    float v = dinv[s] * dinv[d];
    pair[p] = make_int2(s, __float_as_int(v));
}

// ---------------------------------------------------------------------------
// Layer-1 matmul, both branches per block: H[r][2f+0]=z@Wz, H[r][2f+1]=x@Wx.
// Block = 256 threads -> 64 rows x 64 feature-cols. 4x4x2 register tile.
// ---------------------------------------------------------------------------
__global__ __launch_bounds__(256) void k_mm1(const float* __restrict__ Zin,
                                             const float* __restrict__ Xin,
                                             const float* __restrict__ Wz,
                                             const float* __restrict__ Wx,
                                             float* __restrict__ H, int N) {
    __shared__ float Asz[64][20], Asx[64][20];
    __shared__ float Wsz[16][64], Wsx[16][64];
    const int tid = threadIdx.x;
    const int tc = tid & 15, tr = tid >> 4;
    const int row0 = blockIdx.x * 64;
    const int srow = tid >> 2, sk = (tid & 3) * 4;
    const int wk = tid >> 4, wc = (tid & 15) * 4;

    float cz[4][4] = {}, cx[4][4] = {};

    for (int k0 = 0; k0 < 128; k0 += 16) {
        float4 a0 = make_float4(0.f, 0.f, 0.f, 0.f);
        float4 a1 = make_float4(0.f, 0.f, 0.f, 0.f);
        int gr = row0 + srow;
        if (gr < N) {
            a0 = *(const float4*)(Zin + (size_t)gr * 128 + k0 + sk);
            a1 = *(const float4*)(Xin + (size_t)gr * 128 + k0 + sk);
        }
        float4 w0 = *(const float4*)(Wz + (size_t)(k0 + wk) * 64 + wc);
        float4 w1 = *(const float4*)(Wx + (size_t)(k0 + wk) * 64 + wc);
        __syncthreads();
        *(float4*)&Asz[srow][sk] = a0;
        *(float4*)&Asx[srow][sk] = a1;
        *(float4*)&Wsz[wk][wc] = w0;
        *(float4*)&Wsx[wk][wc] = w1;
        __syncthreads();

#pragma unroll
        for (int k = 0; k < 16; k += 4) {
            float4 vz[4], vx[4];
#pragma unroll
            for (int i = 0; i < 4; i++) {
                vz[i] = *(const float4*)&Asz[tr * 4 + i][k];
                vx[i] = *(const float4*)&Asx[tr * 4 + i][k];
            }
#pragma unroll
            for (int kk = 0; kk < 4; kk++) {
                float4 wzv = *(const float4*)&Wsz[k + kk][tc * 4];
                float4 wxv = *(const float4*)&Wsx[k + kk][tc * 4];
#pragma unroll
                for (int i = 0; i < 4; i++) {
                    float a = ((const float*)&vz[i])[kk];
                    float b = ((const float*)&vx[i])[kk];
                    cz[i][0] = fmaf(a, wzv.x, cz[i][0]);
                    cz[i][1] = fmaf(a, wzv.y, cz[i][1]);
                    cz[i][2] = fmaf(a, wzv.z, cz[i][2]);
                    cz[i][3] = fmaf(a, wzv.w, cz[i][3]);
                    cx[i][0] = fmaf(b, wxv.x, cx[i][0]);
                    cx[i][1] = fmaf(b, wxv.y, cx[i][1]);
                    cx[i][2] = fmaf(b, wxv.z, cx[i][2]);
                    cx[i][3] = fmaf(b, wxv.w, cx[i][3]);
                }
            }
        }
    }

#pragma unroll
    for (int i = 0; i < 4; i++) {
        int r = row0 + tr * 4 + i;
        if (r < N) {
            float4 s0 = make_float4(cz[i][0], cx[i][0], cz[i][1], cx[i][1]);
            float4 s1 = make_float4(cz[i][2], cx[i][2], cz[i][3], cx[i][3]);
            *(float4*)(H + (size_t)r * 128 + tc * 8) = s0;
            *(float4*)(H + (size_t)r * 128 + tc * 8 + 4) = s1;
        }
    }
}

// ---------------------------------------------------------------------------
// Layer-2 matmul: A is interleaved [N][128] (z even, x odd), K=64 per branch.
// ---------------------------------------------------------------------------
__global__ __launch_bounds__(256) void k_mm2i(const float* __restrict__ Azx,
                                              const float* __restrict__ Wz,
                                              const float* __restrict__ Wx,
                                              float* __restrict__ H, int N) {
    __shared__ float As[64][36];  // 32 floats (16 interleaved k) + pad
    __shared__ float Wsz[16][64], Wsx[16][64];
    const int tid = threadIdx.x;
    const int tc = tid & 15, tr = tid >> 4;
    const int row0 = blockIdx.x * 64;
    const int srow = tid >> 2, soff = (tid & 3) * 8;
    const int wk = tid >> 4, wc = (tid & 15) * 4;

    float cz[4][4] = {}, cx[4][4] = {};

    for (int k0 = 0; k0 < 64; k0 += 16) {  // k0 in feature units
        float4 a0 = make_float4(0.f, 0.f, 0.f, 0.f);
        float4 a1 = make_float4(0.f, 0.f, 0.f, 0.f);
        int gr = row0 + srow;
        if (gr < N) {
            a0 = *(const float4*)(Azx + (size_t)gr * 128 + 2 * k0 + soff);
            a1 = *(const float4*)(Azx + (size_t)gr * 128 + 2 * k0 + soff + 4);
        }
        float4 w0 = *(const float4*)(Wz + (size_t)(k0 + wk) * 64 + wc);
        float4 w1 = *(const float4*)(Wx + (size_t)(k0 + wk) * 64 + wc);
        __syncthreads();
        *(float4*)&As[srow][soff] = a0;
        *(float4*)&As[srow][soff + 4] = a1;
        *(float4*)&Wsz[wk][wc] = w0;
        *(float4*)&Wsx[wk][wc] = w1;
        __syncthreads();

#pragma unroll
        for (int k = 0; k < 16; k += 2) {
            float4 v[4];  // {z_k, x_k, z_k+1, x_k+1}
#pragma unroll
            for (int i = 0; i < 4; i++) v[i] = *(const float4*)&As[tr * 4 + i][2 * k];
#pragma unroll
            for (int kk = 0; kk < 2; kk++) {
                float4 wzv = *(const float4*)&Wsz[k + kk][tc * 4];
                float4 wxv = *(const float4*)&Wsx[k + kk][tc * 4];
#pragma unroll
                for (int i = 0; i < 4; i++) {
                    float a = kk ? v[i].z : v[i].x;
                    float b = kk ? v[i].w : v[i].y;
                    cz[i][0] = fmaf(a, wzv.x, cz[i][0]);
                    cz[i][1] = fmaf(a, wzv.y, cz[i][1]);
                    cz[i][2] = fmaf(a, wzv.z, cz[i][2]);
                    cz[i][3] = fmaf(a, wzv.w, cz[i][3]);
                    cx[i][0] = fmaf(b, wxv.x, cx[i][0]);
                    cx[i][1] = fmaf(b, wxv.y, cx[i][1]);
                    cx[i][2] = fmaf(b, wxv.z, cx[i][2]);
                    cx[i][3] = fmaf(b, wxv.w, cx[i][3]);
                }
            }
        }
    }

#pragma unroll
    for (int i = 0; i < 4; i++) {
        int r = row0 + tr * 4 + i;
        if (r < N) {
            float4 s0 = make_float4(cz[i][0], cx[i][0], cz[i][1], cx[i][1]);
            float4 s1 = make_float4(cz[i][2], cx[i][2], cz[i][3], cx[i][3]);
            *(float4*)(H + (size_t)r * 128 + tc * 8) = s0;
            *(float4*)(H + (size_t)r * 128 + tc * 8 + 4) = s1;
        }
    }
}

// ---------------------------------------------------------------------------
// Aggregation over interleaved H [N][128]; 1 wave per node, lane = feature,
// edge loop unrolled x4 with independent accumulator chains.
// ---------------------------------------------------------------------------
__global__ __launch_bounds__(256) void k_agg_act(
    const int* __restrict__ rowp, const int2* __restrict__ pair,
    const float* __restrict__ dinv, const float* __restrict__ H,
    const float* __restrict__ bz, const float* __restrict__ bx,
    float* __restrict__ A, int N) {
    int wid = threadIdx.x >> 6, lane = threadIdx.x & 63;
    int i = blockIdx.x * 4 + wid;
    if (i >= N) return;
    int beg = rowp[i], end = rowp[i + 1];
    float sz0 = 0.f, sx0 = 0.f, sz1 = 0.f, sx1 = 0.f;
    int p = beg;
    if ((p & 1) && p < end) {  // align to 16B for int4 pair loads
        int2 cv = pair[p++];
        float2 h = *((const float2*)(H + (size_t)cv.x * 128) + lane);
        float w = __int_as_float(cv.y);
        sz0 = fmaf(w, h.x, sz0);
        sx0 = fmaf(w, h.y, sx0);
    }
    for (; p + 4 <= end; p += 4) {
        int4 pa = *(const int4*)(pair + p);
        int4 pb = *(const int4*)(pair + p + 2);
        float2 h0 = *((const float2*)(H + (size_t)pa.x * 128) + lane);
        float2 h1 = *((const float2*)(H + (size_t)pa.z * 128) + lane);
        float2 h2 = *((const float2*)(H + (size_t)pb.x * 128) + lane);
        float2 h3 = *((const float2*)(H + (size_t)pb.z * 128) + lane);
        float w0 = __int_as_float(pa.y), w1 = __int_as_float(pa.w);
        float w2 = __int_as_float(pb.y), w3 = __int_as_float(pb.w);
        sz0 = fmaf(w0, h0.x, sz0);
        sx0 = fmaf(w0, h0.y, sx0);
        sz1 = fmaf(w1, h1.x, sz1);
        sx1 = fmaf(w1, h1.y, sx1);
        sz0 = fmaf(w2, h2.x, sz0);
        sx0 = fmaf(w2, h2.y, sx0);
        sz1 = fmaf(w3, h3.x, sz1);
        sx1 = fmaf(w3, h3.y, sx1);
    }
    for (; p < end; p++) {
        int2 cv = pair[p];
        float2 h = *((const float2*)(H + (size_t)cv.x * 128) + lane);
        float w = __int_as_float(cv.y);
        sz0 = fmaf(w, h.x, sz0);
        sx0 = fmaf(w, h.y, sx0);
    }
    float sz = sz0 + sz1, sx = sx0 + sx1;
    float dv = dinv[i], sw = dv * dv;
    float2 hs = *((const float2*)(H + (size_t)i * 128) + lane);
    sz = fmaf(sw, hs.x, sz) + bz[lane];
    sx = fmaf(sw, hs.y, sx) + bx[lane];
    sz = sz >= 0.f ? sz : sz * RRELU_SLOPE;
    sx = sx >= 0.f ? sx : sx * RRELU_SLOPE;
    *((float2*)(A + (size_t)i * 128) + lane) = make_float2(sz, sx);
}

__global__ __launch_bounds__(256) void k_agg_final(
    const int* __restrict__ rowp, const int2* __restrict__ pair,
    const float* __restrict__ dinv, const float* __restrict__ H,
    const float* __restrict__ bz, const float* __restrict__ bx,
    const float* __restrict__ Wout, const float* __restrict__ bout,
    float* __restrict__ out, int N) {
    int wid = threadIdx.x >> 6, lane = threadIdx.x & 63;
    int i = blockIdx.x * 4 + wid;
    if (i >= N) return;
    int beg = rowp[i], end = rowp[i + 1];
    float sz0 = 0.f, sx0 = 0.f, sz1 = 0.f, sx1 = 0.f;
    int p = beg;
    if ((p & 1) && p < end) {
        int2 cv = pair[p++];
        float2 h = *((const float2*)(H + (size_t)cv.x * 128) + lane);
        float w = __int_as_float(cv.y);
        sz0 = fmaf(w, h.x, sz0);
        sx0 = fmaf(w, h.y, sx0);
    }
    for (; p + 4 <= end; p += 4) {
        int4 pa = *(const int4*)(pair + p);
        int4 pb = *(const int4*)(pair + p + 2);
        float2 h0 = *((const float2*)(H + (size_t)pa.x * 128) + lane);
        float2 h1 = *((const float2*)(H + (size_t)pa.z * 128) + lane);
        float2 h2 = *((const float2*)(H + (size_t)pb.x * 128) + lane);
        float2 h3 = *((const float2*)(H + (size_t)pb.z * 128) + lane);
        float w0 = __int_as_float(pa.y), w1 = __int_as_float(pa.w);
        float w2 = __int_as_float(pb.y), w3 = __int_as_float(pb.w);
        sz0 = fmaf(w0, h0.x, sz0);
        sx0 = fmaf(w0, h0.y, sx0);
        sz1 = fmaf(w1, h1.x, sz1);
        sx1 = fmaf(w1, h1.y, sx1);
        sz0 = fmaf(w2, h2.x, sz0);
        sx0 = fmaf(w2, h2.y, sx0);
        sz1 = fmaf(w3, h3.x, sz1);
        sx1 = fmaf(w3, h3.y, sx1);
    }
    for (; p < end; p++) {
        int2 cv = pair[p];
        float2 h = *((const float2*)(H + (size_t)cv.x * 128) + lane);
        float w = __int_as_float(cv.y);
        sz0 = fmaf(w, h.x, sz0);
        sx0 = fmaf(w, h.y, sx0);
    }
    float sz = sz0 + sz1, sx = sx0 + sx1;
    float dv = dinv[i], sw = dv * dv;
    float2 hs = *((const float2*)(H + (size_t)i * 128) + lane);
    sz = fmaf(sw, hs.x, sz) + bz[lane];
    sx = fmaf(sw, hs.y, sx) + bx[lane];
    float prod = tanhf(sz) * tanhf(sx) * Wout[lane];
    for (int o = 32; o >= 1; o >>= 1) prod += __shfl_xor(prod, o, 64);
    if (lane == 0) out[i] = prod + bout[0];
}

// ---------------------------------------------------------------------------

extern "C" void kernel_launch(void* const* d_in, const int* in_sizes, int n_in,
                              void* d_out, int out_size, void* d_ws, size_t ws_size,
                              hipStream_t stream) {
    const float* z = (const float*)d_in[0];
    const float* x = (const float*)d_in[1];
    const int* ei = (const int*)d_in[2];
    const float* We1 = (const float*)d_in[3];
    const float* be1 = (const float*)d_in[4];
    const float* We2 = (const float*)d_in[5];
    const float* be2 = (const float*)d_in[6];
    const float* Wf1 = (const float*)d_in[7];
    const float* bf1 = (const float*)d_in[8];
    const float* Wf2 = (const float*)d_in[9];
    const float* bf2 = (const float*)d_in[10];
    const float* Wout = (const float*)d_in[11];
    const float* bout = (const float*)d_in[12];
    float* out = (float*)d_out;

    int N = in_sizes[0] / 128;
    int E = in_sizes[2] / 2;
    const int* src = ei;
    const int* dst = ei + E;

    char* base = (char*)d_ws;
    size_t off = 0;
    auto take = [&](size_t nbytes) -> char* {
        char* p = base + off;
        off = (off + nbytes + 255) & ~(size_t)255;
        return p;
    };
    int NB = (N + 255) / 256;
    int* cnt = (int*)take((size_t)N * 4);
    int* bsum = (int*)take(1024 * 4);
    int* boff = (int*)take(1024 * 4);
    int* rowp = (int*)take(((size_t)N + 1) * 4);
    int* nxt = (int*)take((size_t)N * 4);
    float* dinv = (float*)take((size_t)N * 4);
    int2* pair = (int2*)take((size_t)E * 8);
    float* hzx = (float*)take((size_t)N * 128 * 4);
    float* azx = (float*)take((size_t)N * 128 * 4);

    hipMemsetAsync(cnt, 0, (size_t)N * 4, stream);

    int egrid = (E + 255) / 256;
    k_deg<<<egrid, 256, 0, stream>>>(dst, E, cnt);
    k_scan1<<<NB, 256, 0, stream>>>(cnt, N, bsum);
    k_scan2<<<1, 256, 0, stream>>>(bsum, NB, boff, rowp, N, E);
    k_scan3<<<NB, 256, 0, stream>>>(cnt, boff, N, rowp, nxt, dinv);
    k_fill<<<egrid, 256, 0, stream>>>(src, dst, E, nxt, dinv, pair);

    int mmgrid = (N + 63) / 64;
    int agrid = (N + 3) / 4;

    k_mm1<<<mmgrid, 256, 0, stream>>>(z, x, We1, Wf1, hzx, N);
    k_agg_act<<<agrid, 256, 0, stream>>>(rowp, pair, dinv, hzx, be1, bf1, azx, N);
    k_mm2i<<<mmgrid, 256, 0, stream>>>(azx, We2, Wf2, hzx, N);
    k_agg_final<<<agrid, 256, 0, stream>>>(rowp, pair, dinv, hzx, be2, bf2, Wout,
                                           bout, out, N);
}

// Round 4
// 227.165 us; speedup vs baseline: 2.0173x; 1.2399x over previous
//
#include <hip/hip_runtime.h>
#include <hip/hip_fp16.h>
#include <math.h>

#define RRELU_SLOPE 0.22916667f  // (1/8 + 1/3)/2 = 11/48

// ---------------------------------------------------------------------------
// CSR build: histogram -> scan -> scatter
// ---------------------------------------------------------------------------

__global__ __launch_bounds__(256) void k_deg(const int* __restrict__ dst, int E,
                                             int* __restrict__ cnt) {
    int e = blockIdx.x * 256 + threadIdx.x;
    if (e < E) atomicAdd(&cnt[dst[e]], 1);
}

__global__ __launch_bounds__(256) void k_scan1(const int* __restrict__ cnt, int N,
                                               int* __restrict__ bsum) {
    int i = blockIdx.x * 256 + threadIdx.x;
    int v = (i < N) ? cnt[i] : 0;
    for (int o = 32; o >= 1; o >>= 1) v += __shfl_xor(v, o, 64);
    __shared__ int ws[4];
    if ((threadIdx.x & 63) == 0) ws[threadIdx.x >> 6] = v;
    __syncthreads();
    if (threadIdx.x == 0) bsum[blockIdx.x] = ws[0] + ws[1] + ws[2] + ws[3];
}

__global__ __launch_bounds__(256) void k_scan2(const int* __restrict__ bsum, int NB,
                                               int* __restrict__ boff,
                                               int* __restrict__ rowp, int N, int E) {
    __shared__ int s[256];
    int t = threadIdx.x;
    int v[4];
    int loc = 0;
    for (int i = 0; i < 4; i++) {
        int idx = t * 4 + i;
        v[i] = (idx < NB) ? bsum[idx] : 0;
        loc += v[i];
    }
    s[t] = loc;
    __syncthreads();
    for (int o = 1; o < 256; o <<= 1) {
        int u = (t >= o) ? s[t - o] : 0;
        __syncthreads();
        s[t] += u;
        __syncthreads();
    }
    int excl = s[t] - loc;
    for (int i = 0; i < 4; i++) {
        int idx = t * 4 + i;
        if (idx < NB) { boff[idx] = excl; excl += v[i]; }
    }
    if (t == 0) rowp[N] = E;
}

__global__ __launch_bounds__(256) void k_scan3(const int* __restrict__ cnt,
                                               const int* __restrict__ boff, int N,
                                               int* __restrict__ rowp,
                                               int* __restrict__ nxt,
                                               float* __restrict__ dinv) {
    int i = blockIdx.x * 256 + threadIdx.x;
    int lane = threadIdx.x & 63, wid = threadIdx.x >> 6;
    int v = (i < N) ? cnt[i] : 0;
    int inc = v;
    for (int o = 1; o < 64; o <<= 1) {
        int u = __shfl_up(inc, o, 64);
        if (lane >= o) inc += u;
    }
    __shared__ int wsum[4];
    if (lane == 63) wsum[wid] = inc;
    __syncthreads();
    int wo = 0;
    for (int w = 0; w < wid; w++) wo += wsum[w];
    if (i < N) {
        int excl = inc - v + wo + boff[blockIdx.x];
        rowp[i] = excl;
        nxt[i] = excl;
        dinv[i] = 1.0f / sqrtf((float)v + 1.0f);
    }
}

__global__ __launch_bounds__(256) void k_fill(const int* __restrict__ src,
                                              const int* __restrict__ dst, int E,
                                              int* __restrict__ nxt,
                                              const float* __restrict__ dinv,
                                              int2* __restrict__ pair) {
    int e = blockIdx.x * 256 + threadIdx.x;
    if (e >= E) return;
    int s = src[e], d = dst[e];
    int p = atomicAdd(&nxt[d], 1);
    float v = dinv[s] * dinv[d];
    pair[p] = make_int2(s, __float_as_int(v));
}

// ---------------------------------------------------------------------------
// Layer-1 matmul, both branches per block; output H[r][f] = half2(z_f, x_f).
// Block = 256 threads -> 64 rows x 64 feature-cols. 4x4x2 register tile.
// ---------------------------------------------------------------------------
__global__ __launch_bounds__(256) void k_mm1(const float* __restrict__ Zin,
                                             const float* __restrict__ Xin,
                                             const float* __restrict__ Wz,
                                             const float* __restrict__ Wx,
                                             __half2* __restrict__ H, int N) {
    __shared__ float Asz[64][20], Asx[64][20];
    __shared__ float Wsz[16][64], Wsx[16][64];
    const int tid = threadIdx.x;
    const int tc = tid & 15, tr = tid >> 4;
    const int row0 = blockIdx.x * 64;
    const int srow = tid >> 2, sk = (tid & 3) * 4;
    const int wk = tid >> 4, wc = (tid & 15) * 4;

    float cz[4][4] = {}, cx[4][4] = {};

    for (int k0 = 0; k0 < 128; k0 += 16) {
        float4 a0 = make_float4(0.f, 0.f, 0.f, 0.f);
        float4 a1 = make_float4(0.f, 0.f, 0.f, 0.f);
        int gr = row0 + srow;
        if (gr < N) {
            a0 = *(const float4*)(Zin + (size_t)gr * 128 + k0 + sk);
            a1 = *(const float4*)(Xin + (size_t)gr * 128 + k0 + sk);
        }
        float4 w0 = *(const float4*)(Wz + (size_t)(k0 + wk) * 64 + wc);
        float4 w1 = *(const float4*)(Wx + (size_t)(k0 + wk) * 64 + wc);
        __syncthreads();
        *(float4*)&Asz[srow][sk] = a0;
        *(float4*)&Asx[srow][sk] = a1;
        *(float4*)&Wsz[wk][wc] = w0;
        *(float4*)&Wsx[wk][wc] = w1;
        __syncthreads();

#pragma unroll
        for (int k = 0; k < 16; k += 4) {
            float4 vz[4], vx[4];
#pragma unroll
            for (int i = 0; i < 4; i++) {
                vz[i] = *(const float4*)&Asz[tr * 4 + i][k];
                vx[i] = *(const float4*)&Asx[tr * 4 + i][k];
            }
#pragma unroll
            for (int kk = 0; kk < 4; kk++) {
                float4 wzv = *(const float4*)&Wsz[k + kk][tc * 4];
                float4 wxv = *(const float4*)&Wsx[k + kk][tc * 4];
#pragma unroll
                for (int i = 0; i < 4; i++) {
                    float a = ((const float*)&vz[i])[kk];
                    float b = ((const float*)&vx[i])[kk];
                    cz[i][0] = fmaf(a, wzv.x, cz[i][0]);
                    cz[i][1] = fmaf(a, wzv.y, cz[i][1]);
                    cz[i][2] = fmaf(a, wzv.z, cz[i][2]);
                    cz[i][3] = fmaf(a, wzv.w, cz[i][3]);
                    cx[i][0] = fmaf(b, wxv.x, cx[i][0]);
                    cx[i][1] = fmaf(b, wxv.y, cx[i][1]);
                    cx[i][2] = fmaf(b, wxv.z, cx[i][2]);
                    cx[i][3] = fmaf(b, wxv.w, cx[i][3]);
                }
            }
        }
    }

#pragma unroll
    for (int i = 0; i < 4; i++) {
        int r = row0 + tr * 4 + i;
        if (r < N) {
            union { __half2 h[4]; float4 f; } u;
#pragma unroll
            for (int j = 0; j < 4; j++) u.h[j] = __floats2half2_rn(cz[i][j], cx[i][j]);
            *(float4*)(H + (size_t)r * 64 + tc * 4) = u.f;
        }
    }
}

// ---------------------------------------------------------------------------
// Layer-2 matmul: A is interleaved f32 [N][128] (z even, x odd), K=64/branch;
// output half2 like k_mm1.
// ---------------------------------------------------------------------------
__global__ __launch_bounds__(256) void k_mm2i(const float* __restrict__ Azx,
                                              const float* __restrict__ Wz,
                                              const float* __restrict__ Wx,
                                              __half2* __restrict__ H, int N) {
    __shared__ float As[64][36];
    __shared__ float Wsz[16][64], Wsx[16][64];
    const int tid = threadIdx.x;
    const int tc = tid & 15, tr = tid >> 4;
    const int row0 = blockIdx.x * 64;
    const int srow = tid >> 2, soff = (tid & 3) * 8;
    const int wk = tid >> 4, wc = (tid & 15) * 4;

    float cz[4][4] = {}, cx[4][4] = {};

    for (int k0 = 0; k0 < 64; k0 += 16) {
        float4 a0 = make_float4(0.f, 0.f, 0.f, 0.f);
        float4 a1 = make_float4(0.f, 0.f, 0.f, 0.f);
        int gr = row0 + srow;
        if (gr < N) {
            a0 = *(const float4*)(Azx + (size_t)gr * 128 + 2 * k0 + soff);
            a1 = *(const float4*)(Azx + (size_t)gr * 128 + 2 * k0 + soff + 4);
        }
        float4 w0 = *(const float4*)(Wz + (size_t)(k0 + wk) * 64 + wc);
        float4 w1 = *(const float4*)(Wx + (size_t)(k0 + wk) * 64 + wc);
        __syncthreads();
        *(float4*)&As[srow][soff] = a0;
        *(float4*)&As[srow][soff + 4] = a1;
        *(float4*)&Wsz[wk][wc] = w0;
        *(float4*)&Wsx[wk][wc] = w1;
        __syncthreads();

#pragma unroll
        for (int k = 0; k < 16; k += 2) {
            float4 v[4];
#pragma unroll
            for (int i = 0; i < 4; i++) v[i] = *(const float4*)&As[tr * 4 + i][2 * k];
#pragma unroll
            for (int kk = 0; kk < 2; kk++) {
                float4 wzv = *(const float4*)&Wsz[k + kk][tc * 4];
                float4 wxv = *(const float4*)&Wsx[k + kk][tc * 4];
#pragma unroll
                for (int i = 0; i < 4; i++) {
                    float a = kk ? v[i].z : v[i].x;
                    float b = kk ? v[i].w : v[i].y;
                    cz[i][0] = fmaf(a, wzv.x, cz[i][0]);
                    cz[i][1] = fmaf(a, wzv.y, cz[i][1]);
                    cz[i][2] = fmaf(a, wzv.z, cz[i][2]);
                    cz[i][3] = fmaf(a, wzv.w, cz[i][3]);
                    cx[i][0] = fmaf(b, wxv.x, cx[i][0]);
                    cx[i][1] = fmaf(b, wxv.y, cx[i][1]);
                    cx[i][2] = fmaf(b, wxv.z, cx[i][2]);
                    cx[i][3] = fmaf(b, wxv.w, cx[i][3]);
                }
            }
        }
    }

#pragma unroll
    for (int i = 0; i < 4; i++) {
        int r = row0 + tr * 4 + i;
        if (r < N) {
            union { __half2 h[4]; float4 f; } u;
#pragma unroll
            for (int j = 0; j < 4; j++) u.h[j] = __floats2half2_rn(cz[i][j], cx[i][j]);
            *(float4*)(H + (size_t)r * 64 + tc * 4) = u.f;
        }
    }
}

// ---------------------------------------------------------------------------
// Aggregation over half2 H [N][64]; 1 wave per node, lane = feature pair,
// 8 gathers in flight, 4 accumulator chains, all accumulation f32.
// ---------------------------------------------------------------------------
__global__ __launch_bounds__(256) void k_agg_act(
    const int* __restrict__ rowp, const int2* __restrict__ pair,
    const float* __restrict__ dinv, const __half2* __restrict__ H,
    const float* __restrict__ bz, const float* __restrict__ bx,
    float* __restrict__ A, int N) {
    int wid = threadIdx.x >> 6, lane = threadIdx.x & 63;
    int i = blockIdx.x * 4 + wid;
    if (i >= N) return;
    int beg = rowp[i], end = rowp[i + 1];
    float2 s0 = {0.f, 0.f}, s1 = {0.f, 0.f}, s2 = {0.f, 0.f}, s3 = {0.f, 0.f};
    int p = beg;
    if (p < end && (p & 1)) {
        int2 cv = pair[p++];
        float2 h = __half22float2(H[(size_t)cv.x * 64 + lane]);
        float w = __int_as_float(cv.y);
        s0.x = fmaf(w, h.x, s0.x);
        s0.y = fmaf(w, h.y, s0.y);
    }
    for (; p + 8 <= end; p += 8) {
        int4 pa = *(const int4*)(pair + p);
        int4 pb = *(const int4*)(pair + p + 2);
        int4 pc = *(const int4*)(pair + p + 4);
        int4 pd = *(const int4*)(pair + p + 6);
        float2 h0 = __half22float2(H[(size_t)pa.x * 64 + lane]);
        float2 h1 = __half22float2(H[(size_t)pa.z * 64 + lane]);
        float2 h2 = __half22float2(H[(size_t)pb.x * 64 + lane]);
        float2 h3 = __half22float2(H[(size_t)pb.z * 64 + lane]);
        float2 h4 = __half22float2(H[(size_t)pc.x * 64 + lane]);
        float2 h5 = __half22float2(H[(size_t)pc.z * 64 + lane]);
        float2 h6 = __half22float2(H[(size_t)pd.x * 64 + lane]);
        float2 h7 = __half22float2(H[(size_t)pd.z * 64 + lane]);
        float w0 = __int_as_float(pa.y), w1 = __int_as_float(pa.w);
        float w2 = __int_as_float(pb.y), w3 = __int_as_float(pb.w);
        float w4 = __int_as_float(pc.y), w5 = __int_as_float(pc.w);
        float w6 = __int_as_float(pd.y), w7 = __int_as_float(pd.w);
        s0.x = fmaf(w0, h0.x, s0.x); s0.y = fmaf(w0, h0.y, s0.y);
        s1.x = fmaf(w1, h1.x, s1.x); s1.y = fmaf(w1, h1.y, s1.y);
        s2.x = fmaf(w2, h2.x, s2.x); s2.y = fmaf(w2, h2.y, s2.y);
        s3.x = fmaf(w3, h3.x, s3.x); s3.y = fmaf(w3, h3.y, s3.y);
        s0.x = fmaf(w4, h4.x, s0.x); s0.y = fmaf(w4, h4.y, s0.y);
        s1.x = fmaf(w5, h5.x, s1.x); s1.y = fmaf(w5, h5.y, s1.y);
        s2.x = fmaf(w6, h6.x, s2.x); s2.y = fmaf(w6, h6.y, s2.y);
        s3.x = fmaf(w7, h7.x, s3.x); s3.y = fmaf(w7, h7.y, s3.y);
    }
    for (; p + 2 <= end; p += 2) {
        int4 pa = *(const int4*)(pair + p);
        float2 h0 = __half22float2(H[(size_t)pa.x * 64 + lane]);
        float2 h1 = __half22float2(H[(size_t)pa.z * 64 + lane]);
        float w0 = __int_as_float(pa.y), w1 = __int_as_float(pa.w);
        s0.x = fmaf(w0, h0.x, s0.x); s0.y = fmaf(w0, h0.y, s0.y);
        s1.x = fmaf(w1, h1.x, s1.x); s1.y = fmaf(w1, h1.y, s1.y);
    }
    if (p < end) {
        int2 cv = pair[p];
        float2 h = __half22float2(H[(size_t)cv.x * 64 + lane]);
        float w = __int_as_float(cv.y);
        s0.x = fmaf(w, h.x, s0.x);
        s0.y = fmaf(w, h.y, s0.y);
    }
    float sz = (s0.x + s1.x) + (s2.x + s3.x);
    float sx = (s0.y + s1.y) + (s2.y + s3.y);
    float dv = dinv[i], sw = dv * dv;
    float2 hs = __half22float2(H[(size_t)i * 64 + lane]);
    sz = fmaf(sw, hs.x, sz) + bz[lane];
    sx = fmaf(sw, hs.y, sx) + bx[lane];
    sz = sz >= 0.f ? sz : sz * RRELU_SLOPE;
    sx = sx >= 0.f ? sx : sx * RRELU_SLOPE;
    *((float2*)(A + (size_t)i * 128) + lane) = make_float2(sz, sx);
}

__global__ __launch_bounds__(256) void k_agg_final(
    const int* __restrict__ rowp, const int2* __restrict__ pair,
    const float* __restrict__ dinv, const __half2* __restrict__ H,
    const float* __restrict__ bz, const float* __restrict__ bx,
    const float* __restrict__ Wout, const float* __restrict__ bout,
    float* __restrict__ out, int N) {
    int wid = threadIdx.x >> 6, lane = threadIdx.x & 63;
    int i = blockIdx.x * 4 + wid;
    if (i >= N) return;
    int beg = rowp[i], end = rowp[i + 1];
    float2 s0 = {0.f, 0.f}, s1 = {0.f, 0.f}, s2 = {0.f, 0.f}, s3 = {0.f, 0.f};
    int p = beg;
    if (p < end && (p & 1)) {
        int2 cv = pair[p++];
        float2 h = __half22float2(H[(size_t)cv.x * 64 + lane]);
        float w = __int_as_float(cv.y);
        s0.x = fmaf(w, h.x, s0.x);
        s0.y = fmaf(w, h.y, s0.y);
    }
    for (; p + 8 <= end; p += 8) {
        int4 pa = *(const int4*)(pair + p);
        int4 pb = *(const int4*)(pair + p + 2);
        int4 pc = *(const int4*)(pair + p + 4);
        int4 pd = *(const int4*)(pair + p + 6);
        float2 h0 = __half22float2(H[(size_t)pa.x * 64 + lane]);
        float2 h1 = __half22float2(H[(size_t)pa.z * 64 + lane]);
        float2 h2 = __half22float2(H[(size_t)pb.x * 64 + lane]);
        float2 h3 = __half22float2(H[(size_t)pb.z * 64 + lane]);
        float2 h4 = __half22float2(H[(size_t)pc.x * 64 + lane]);
        float2 h5 = __half22float2(H[(size_t)pc.z * 64 + lane]);
        float2 h6 = __half22float2(H[(size_t)pd.x * 64 + lane]);
        float2 h7 = __half22float2(H[(size_t)pd.z * 64 + lane]);
        float w0 = __int_as_float(pa.y), w1 = __int_as_float(pa.w);
        float w2 = __int_as_float(pb.y), w3 = __int_as_float(pb.w);
        float w4 = __int_as_float(pc.y), w5 = __int_as_float(pc.w);
        float w6 = __int_as_float(pd.y), w7 = __int_as_float(pd.w);
        s0.x = fmaf(w0, h0.x, s0.x); s0.y = fmaf(w0, h0.y, s0.y);
        s1.x = fmaf(w1, h1.x, s1.x); s1.y = fmaf(w1, h1.y, s1.y);
        s2.x = fmaf(w2, h2.x, s2.x); s2.y = fmaf(w2, h2.y, s2.y);
        s3.x = fmaf(w3, h3.x, s3.x); s3.y = fmaf(w3, h3.y, s3.y);
        s0.x = fmaf(w4, h4.x, s0.x); s0.y = fmaf(w4, h4.y, s0.y);
        s1.x = fmaf(w5, h5.x, s1.x); s1.y = fmaf(w5, h5.y, s1.y);
        s2.x = fmaf(w6, h6.x, s2.x); s2.y = fmaf(w6, h6.y, s2.y);
        s3.x = fmaf(w7, h7.x, s3.x); s3.y = fmaf(w7, h7.y, s3.y);
    }
    for (; p + 2 <= end; p += 2) {
        int4 pa = *(const int4*)(pair + p);
        float2 h0 = __half22float2(H[(size_t)pa.x * 64 + lane]);
        float2 h1 = __half22float2(H[(size_t)pa.z * 64 + lane]);
        float w0 = __int_as_float(pa.y), w1 = __int_as_float(pa.w);
        s0.x = fmaf(w0, h0.x, s0.x); s0.y = fmaf(w0, h0.y, s0.y);
        s1.x = fmaf(w1, h1.x, s1.x); s1.y = fmaf(w1, h1.y, s1.y);
    }
    if (p < end) {
        int2 cv = pair[p];
        float2 h = __half22float2(H[(size_t)cv.x * 64 + lane]);
        float w = __int_as_float(cv.y);
        s0.x = fmaf(w, h.x, s0.x);
        s0.y = fmaf(w, h.y, s0.y);
    }
    float sz = (s0.x + s1.x) + (s2.x + s3.x);
    float sx = (s0.y + s1.y) + (s2.y + s3.y);
    float dv = dinv[i], sw = dv * dv;
    float2 hs = __half22float2(H[(size_t)i * 64 + lane]);
    sz = fmaf(sw, hs.x, sz) + bz[lane];
    sx = fmaf(sw, hs.y, sx) + bx[lane];
    float prod = tanhf(sz) * tanhf(sx) * Wout[lane];
    for (int o = 32; o >= 1; o >>= 1) prod += __shfl_xor(prod, o, 64);
    if (lane == 0) out[i] = prod + bout[0];
}

// ---------------------------------------------------------------------------

extern "C" void kernel_launch(void* const* d_in, const int* in_sizes, int n_in,
                              void* d_out, int out_size, void* d_ws, size_t ws_size,
                              hipStream_t stream) {
    const float* z = (const float*)d_in[0];
    const float* x = (const float*)d_in[1];
    const int* ei = (const int*)d_in[2];
    const float* We1 = (const float*)d_in[3];
    const float* be1 = (const float*)d_in[4];
    const float* We2 = (const float*)d_in[5];
    const float* be2 = (const float*)d_in[6];
    const float* Wf1 = (const float*)d_in[7];
    const float* bf1 = (const float*)d_in[8];
    const float* Wf2 = (const float*)d_in[9];
    const float* bf2 = (const float*)d_in[10];
    const float* Wout = (const float*)d_in[11];
    const float* bout = (const float*)d_in[12];
    float* out = (float*)d_out;

    int N = in_sizes[0] / 128;
    int E = in_sizes[2] / 2;
    const int* src = ei;
    const int* dst = ei + E;

    char* base = (char*)d_ws;
    size_t off = 0;
    auto take = [&](size_t nbytes) -> char* {
        char* p = base + off;
        off = (off + nbytes + 255) & ~(size_t)255;
        return p;
    };
    int NB = (N + 255) / 256;
    int* cnt = (int*)take((size_t)N * 4);
    int* bsum = (int*)take(1024 * 4);
    int* boff = (int*)take(1024 * 4);
    int* rowp = (int*)take(((size_t)N + 1) * 4);
    int* nxt = (int*)take((size_t)N * 4);
    float* dinv = (float*)take((size_t)N * 4);
    int2* pair = (int2*)take((size_t)E * 8);
    __half2* hzx = (__half2*)take((size_t)N * 64 * 4);
    float* azx = (float*)take((size_t)N * 128 * 4);

    hipMemsetAsync(cnt, 0, (size_t)N * 4, stream);

    int egrid = (E + 255) / 256;
    k_deg<<<egrid, 256, 0, stream>>>(dst, E, cnt);
    k_scan1<<<NB, 256, 0, stream>>>(cnt, N, bsum);
    k_scan2<<<1, 256, 0, stream>>>(bsum, NB, boff, rowp, N, E);
    k_scan3<<<NB, 256, 0, stream>>>(cnt, boff, N, rowp, nxt, dinv);
    k_fill<<<egrid, 256, 0, stream>>>(src, dst, E, nxt, dinv, pair);

    int mmgrid = (N + 63) / 64;
    int agrid = (N + 3) / 4;

    k_mm1<<<mmgrid, 256, 0, stream>>>(z, x, We1, Wf1, hzx, N);
    k_agg_act<<<agrid, 256, 0, stream>>>(rowp, pair, dinv, hzx, be1, bf1, azx, N);
    k_mm2i<<<mmgrid, 256, 0, stream>>>(azx, We2, Wf2, hzx, N);
    k_agg_final<<<agrid, 256, 0, stream>>>(rowp, pair, dinv, hzx, be2, bf2, Wout,
                                           bout, out, N);
}

// Round 5
// 203.491 us; speedup vs baseline: 2.2520x; 1.1163x over previous
//
#include <hip/hip_runtime.h>
#include <hip/hip_fp16.h>
#include <math.h>

#define RRELU_SLOPE 0.22916667f  // (1/8 + 1/3)/2 = 11/48

// ---------------------------------------------------------------------------
// CSR build: histogram(+rank) -> scan -> rank-based scatter (no atomic)
// ---------------------------------------------------------------------------

__global__ __launch_bounds__(256) void k_deg(const int* __restrict__ dst, int E,
                                             int* __restrict__ cnt,
                                             int* __restrict__ rank) {
    int e = blockIdx.x * 256 + threadIdx.x;
    if (e < E) rank[e] = atomicAdd(&cnt[dst[e]], 1);
}

__global__ __launch_bounds__(256) void k_scan1(const int* __restrict__ cnt, int N,
                                               int* __restrict__ bsum) {
    int i = blockIdx.x * 256 + threadIdx.x;
    int v = (i < N) ? cnt[i] : 0;
    for (int o = 32; o >= 1; o >>= 1) v += __shfl_xor(v, o, 64);
    __shared__ int ws[4];
    if ((threadIdx.x & 63) == 0) ws[threadIdx.x >> 6] = v;
    __syncthreads();
    if (threadIdx.x == 0) bsum[blockIdx.x] = ws[0] + ws[1] + ws[2] + ws[3];
}

__global__ __launch_bounds__(256) void k_scan2(const int* __restrict__ bsum, int NB,
                                               int* __restrict__ boff,
                                               int* __restrict__ rowp, int N, int E) {
    __shared__ int s[256];
    int t = threadIdx.x;
    int v[4];
    int loc = 0;
    for (int i = 0; i < 4; i++) {
        int idx = t * 4 + i;
        v[i] = (idx < NB) ? bsum[idx] : 0;
        loc += v[i];
    }
    s[t] = loc;
    __syncthreads();
    for (int o = 1; o < 256; o <<= 1) {
        int u = (t >= o) ? s[t - o] : 0;
        __syncthreads();
        s[t] += u;
        __syncthreads();
    }
    int excl = s[t] - loc;
    for (int i = 0; i < 4; i++) {
        int idx = t * 4 + i;
        if (idx < NB) { boff[idx] = excl; excl += v[i]; }
    }
    if (t == 0) rowp[N] = E;
}

__global__ __launch_bounds__(256) void k_scan3(const int* __restrict__ cnt,
                                               const int* __restrict__ boff, int N,
                                               int* __restrict__ rowp,
                                               float* __restrict__ dinv) {
    int i = blockIdx.x * 256 + threadIdx.x;
    int lane = threadIdx.x & 63, wid = threadIdx.x >> 6;
    int v = (i < N) ? cnt[i] : 0;
    int inc = v;
    for (int o = 1; o < 64; o <<= 1) {
        int u = __shfl_up(inc, o, 64);
        if (lane >= o) inc += u;
    }
    __shared__ int wsum[4];
    if (lane == 63) wsum[wid] = inc;
    __syncthreads();
    int wo = 0;
    for (int w = 0; w < wid; w++) wo += wsum[w];
    if (i < N) {
        int excl = inc - v + wo + boff[blockIdx.x];
        rowp[i] = excl;
        dinv[i] = 1.0f / sqrtf((float)v + 1.0f);
    }
}

// slot = rowp[dst] + rank ; payload = src only (4B)
__global__ __launch_bounds__(256) void k_fill(const int* __restrict__ src,
                                              const int* __restrict__ dst,
                                              const int* __restrict__ rank, int E,
                                              const int* __restrict__ rowp,
                                              int* __restrict__ csrc) {
    int e = blockIdx.x * 256 + threadIdx.x;
    if (e >= E) return;
    int d = dst[e];
    csrc[rowp[d] + rank[e]] = src[e];
}

// ---------------------------------------------------------------------------
// Layer-1 matmul, both branches per block; output H[r][f] = half2(z_f, x_f).
// ---------------------------------------------------------------------------
__global__ __launch_bounds__(256) void k_mm1(const float* __restrict__ Zin,
                                             const float* __restrict__ Xin,
                                             const float* __restrict__ Wz,
                                             const float* __restrict__ Wx,
                                             __half2* __restrict__ H, int N) {
    __shared__ float Asz[64][20], Asx[64][20];
    __shared__ float Wsz[16][64], Wsx[16][64];
    const int tid = threadIdx.x;
    const int tc = tid & 15, tr = tid >> 4;
    const int row0 = blockIdx.x * 64;
    const int srow = tid >> 2, sk = (tid & 3) * 4;
    const int wk = tid >> 4, wc = (tid & 15) * 4;

    float cz[4][4] = {}, cx[4][4] = {};

    for (int k0 = 0; k0 < 128; k0 += 16) {
        float4 a0 = make_float4(0.f, 0.f, 0.f, 0.f);
        float4 a1 = make_float4(0.f, 0.f, 0.f, 0.f);
        int gr = row0 + srow;
        if (gr < N) {
            a0 = *(const float4*)(Zin + (size_t)gr * 128 + k0 + sk);
            a1 = *(const float4*)(Xin + (size_t)gr * 128 + k0 + sk);
        }
        float4 w0 = *(const float4*)(Wz + (size_t)(k0 + wk) * 64 + wc);
        float4 w1 = *(const float4*)(Wx + (size_t)(k0 + wk) * 64 + wc);
        __syncthreads();
        *(float4*)&Asz[srow][sk] = a0;
        *(float4*)&Asx[srow][sk] = a1;
        *(float4*)&Wsz[wk][wc] = w0;
        *(float4*)&Wsx[wk][wc] = w1;
        __syncthreads();

#pragma unroll
        for (int k = 0; k < 16; k += 4) {
            float4 vz[4], vx[4];
#pragma unroll
            for (int i = 0; i < 4; i++) {
                vz[i] = *(const float4*)&Asz[tr * 4 + i][k];
                vx[i] = *(const float4*)&Asx[tr * 4 + i][k];
            }
#pragma unroll
            for (int kk = 0; kk < 4; kk++) {
                float4 wzv = *(const float4*)&Wsz[k + kk][tc * 4];
                float4 wxv = *(const float4*)&Wsx[k + kk][tc * 4];
#pragma unroll
                for (int i = 0; i < 4; i++) {
                    float a = ((const float*)&vz[i])[kk];
                    float b = ((const float*)&vx[i])[kk];
                    cz[i][0] = fmaf(a, wzv.x, cz[i][0]);
                    cz[i][1] = fmaf(a, wzv.y, cz[i][1]);
                    cz[i][2] = fmaf(a, wzv.z, cz[i][2]);
                    cz[i][3] = fmaf(a, wzv.w, cz[i][3]);
                    cx[i][0] = fmaf(b, wxv.x, cx[i][0]);
                    cx[i][1] = fmaf(b, wxv.y, cx[i][1]);
                    cx[i][2] = fmaf(b, wxv.z, cx[i][2]);
                    cx[i][3] = fmaf(b, wxv.w, cx[i][3]);
                }
            }
        }
    }

#pragma unroll
    for (int i = 0; i < 4; i++) {
        int r = row0 + tr * 4 + i;
        if (r < N) {
            union { __half2 h[4]; float4 f; } u;
#pragma unroll
            for (int j = 0; j < 4; j++) u.h[j] = __floats2half2_rn(cz[i][j], cx[i][j]);
            *(float4*)(H + (size_t)r * 64 + tc * 4) = u.f;
        }
    }
}

// ---------------------------------------------------------------------------
// Layer-2 matmul: A interleaved f32 [N][128], K=64/branch; half2 output.
// ---------------------------------------------------------------------------
__global__ __launch_bounds__(256) void k_mm2i(const float* __restrict__ Azx,
                                              const float* __restrict__ Wz,
                                              const float* __restrict__ Wx,
                                              __half2* __restrict__ H, int N) {
    __shared__ float As[64][36];
    __shared__ float Wsz[16][64], Wsx[16][64];
    const int tid = threadIdx.x;
    const int tc = tid & 15, tr = tid >> 4;
    const int row0 = blockIdx.x * 64;
    const int srow = tid >> 2, soff = (tid & 3) * 8;
    const int wk = tid >> 4, wc = (tid & 15) * 4;

    float cz[4][4] = {}, cx[4][4] = {};

    for (int k0 = 0; k0 < 64; k0 += 16) {
        float4 a0 = make_float4(0.f, 0.f, 0.f, 0.f);
        float4 a1 = make_float4(0.f, 0.f, 0.f, 0.f);
        int gr = row0 + srow;
        if (gr < N) {
            a0 = *(const float4*)(Azx + (size_t)gr * 128 + 2 * k0 + soff);
            a1 = *(const float4*)(Azx + (size_t)gr * 128 + 2 * k0 + soff + 4);
        }
        float4 w0 = *(const float4*)(Wz + (size_t)(k0 + wk) * 64 + wc);
        float4 w1 = *(const float4*)(Wx + (size_t)(k0 + wk) * 64 + wc);
        __syncthreads();
        *(float4*)&As[srow][soff] = a0;
        *(float4*)&As[srow][soff + 4] = a1;
        *(float4*)&Wsz[wk][wc] = w0;
        *(float4*)&Wsx[wk][wc] = w1;
        __syncthreads();

#pragma unroll
        for (int k = 0; k < 16; k += 2) {
            float4 v[4];
#pragma unroll
            for (int i = 0; i < 4; i++) v[i] = *(const float4*)&As[tr * 4 + i][2 * k];
#pragma unroll
            for (int kk = 0; kk < 2; kk++) {
                float4 wzv = *(const float4*)&Wsz[k + kk][tc * 4];
                float4 wxv = *(const float4*)&Wsx[k + kk][tc * 4];
#pragma unroll
                for (int i = 0; i < 4; i++) {
                    float a = kk ? v[i].z : v[i].x;
                    float b = kk ? v[i].w : v[i].y;
                    cz[i][0] = fmaf(a, wzv.x, cz[i][0]);
                    cz[i][1] = fmaf(a, wzv.y, cz[i][1]);
                    cz[i][2] = fmaf(a, wzv.z, cz[i][2]);
                    cz[i][3] = fmaf(a, wzv.w, cz[i][3]);
                    cx[i][0] = fmaf(b, wxv.x, cx[i][0]);
                    cx[i][1] = fmaf(b, wxv.y, cx[i][1]);
                    cx[i][2] = fmaf(b, wxv.z, cx[i][2]);
                    cx[i][3] = fmaf(b, wxv.w, cx[i][3]);
                }
            }
        }
    }

#pragma unroll
    for (int i = 0; i < 4; i++) {
        int r = row0 + tr * 4 + i;
        if (r < N) {
            union { __half2 h[4]; float4 f; } u;
#pragma unroll
            for (int j = 0; j < 4; j++) u.h[j] = __floats2half2_rn(cz[i][j], cx[i][j]);
            *(float4*)(H + (size_t)r * 64 + tc * 4) = u.f;
        }
    }
}

// ---------------------------------------------------------------------------
// Aggregation over half2 H [N][64]; 1 wave/node, lane = feature pair,
// csrc holds src ids only; norm = dinv[src]*dinv[dst] computed on the fly.
// 8 gathers in flight, 4 accumulator chains, all accumulation f32.
// ---------------------------------------------------------------------------
#define AGG_EDGE(S, C)                                            \
    {                                                             \
        float2 h_ = __half22float2(H[(size_t)(C)*64 + lane]);     \
        float w_ = dinv[C] * dvi;                                 \
        S.x = fmaf(w_, h_.x, S.x);                                \
        S.y = fmaf(w_, h_.y, S.y);                                \
    }

__global__ __launch_bounds__(256) void k_agg_act(
    const int* __restrict__ rowp, const int* __restrict__ csrc,
    const float* __restrict__ dinv, const __half2* __restrict__ H,
    const float* __restrict__ bz, const float* __restrict__ bx,
    float* __restrict__ A, int N) {
    int wid = threadIdx.x >> 6, lane = threadIdx.x & 63;
    int i = blockIdx.x * 4 + wid;
    if (i >= N) return;
    int beg = rowp[i], end = rowp[i + 1];
    float dvi = dinv[i];
    float2 s0 = {0.f, 0.f}, s1 = {0.f, 0.f}, s2 = {0.f, 0.f}, s3 = {0.f, 0.f};
    int p = beg;
    while (p < end && (p & 3)) {  // align to 16B
        int c = csrc[p++];
        AGG_EDGE(s0, c);
    }
    for (; p + 8 <= end; p += 8) {
        int4 ca = *(const int4*)(csrc + p);
        int4 cb = *(const int4*)(csrc + p + 4);
        AGG_EDGE(s0, ca.x);
        AGG_EDGE(s1, ca.y);
        AGG_EDGE(s2, ca.z);
        AGG_EDGE(s3, ca.w);
        AGG_EDGE(s0, cb.x);
        AGG_EDGE(s1, cb.y);
        AGG_EDGE(s2, cb.z);
        AGG_EDGE(s3, cb.w);
    }
    if (p + 4 <= end) {
        int4 ca = *(const int4*)(csrc + p);
        AGG_EDGE(s0, ca.x);
        AGG_EDGE(s1, ca.y);
        AGG_EDGE(s2, ca.z);
        AGG_EDGE(s3, ca.w);
        p += 4;
    }
    while (p < end) {
        int c = csrc[p++];
        AGG_EDGE(s0, c);
    }
    float sz = (s0.x + s1.x) + (s2.x + s3.x);
    float sx = (s0.y + s1.y) + (s2.y + s3.y);
    float sw = dvi * dvi;
    float2 hs = __half22float2(H[(size_t)i * 64 + lane]);
    sz = fmaf(sw, hs.x, sz) + bz[lane];
    sx = fmaf(sw, hs.y, sx) + bx[lane];
    sz = sz >= 0.f ? sz : sz * RRELU_SLOPE;
    sx = sx >= 0.f ? sx : sx * RRELU_SLOPE;
    *((float2*)(A + (size_t)i * 128) + lane) = make_float2(sz, sx);
}

__global__ __launch_bounds__(256) void k_agg_final(
    const int* __restrict__ rowp, const int* __restrict__ csrc,
    const float* __restrict__ dinv, const __half2* __restrict__ H,
    const float* __restrict__ bz, const float* __restrict__ bx,
    const float* __restrict__ Wout, const float* __restrict__ bout,
    float* __restrict__ out, int N) {
    int wid = threadIdx.x >> 6, lane = threadIdx.x & 63;
    int i = blockIdx.x * 4 + wid;
    if (i >= N) return;
    int beg = rowp[i], end = rowp[i + 1];
    float dvi = dinv[i];
    float2 s0 = {0.f, 0.f}, s1 = {0.f, 0.f}, s2 = {0.f, 0.f}, s3 = {0.f, 0.f};
    int p = beg;
    while (p < end && (p & 3)) {
        int c = csrc[p++];
        AGG_EDGE(s0, c);
    }
    for (; p + 8 <= end; p += 8) {
        int4 ca = *(const int4*)(csrc + p);
        int4 cb = *(const int4*)(csrc + p + 4);
        AGG_EDGE(s0, ca.x);
        AGG_EDGE(s1, ca.y);
        AGG_EDGE(s2, ca.z);
        AGG_EDGE(s3, ca.w);
        AGG_EDGE(s0, cb.x);
        AGG_EDGE(s1, cb.y);
        AGG_EDGE(s2, cb.z);
        AGG_EDGE(s3, cb.w);
    }
    if (p + 4 <= end) {
        int4 ca = *(const int4*)(csrc + p);
        AGG_EDGE(s0, ca.x);
        AGG_EDGE(s1, ca.y);
        AGG_EDGE(s2, ca.z);
        AGG_EDGE(s3, ca.w);
        p += 4;
    }
    while (p < end) {
        int c = csrc[p++];
        AGG_EDGE(s0, c);
    }
    float sz = (s0.x + s1.x) + (s2.x + s3.x);
    float sx = (s0.y + s1.y) + (s2.y + s3.y);
    float sw = dvi * dvi;
    float2 hs = __half22float2(H[(size_t)i * 64 + lane]);
    sz = fmaf(sw, hs.x, sz) + bz[lane];
    sx = fmaf(sw, hs.y, sx) + bx[lane];
    float prod = tanhf(sz) * tanhf(sx) * Wout[lane];
    for (int o = 32; o >= 1; o >>= 1) prod += __shfl_xor(prod, o, 64);
    if (lane == 0) out[i] = prod + bout[0];
}

// ---------------------------------------------------------------------------

extern "C" void kernel_launch(void* const* d_in, const int* in_sizes, int n_in,
                              void* d_out, int out_size, void* d_ws, size_t ws_size,
                              hipStream_t stream) {
    const float* z = (const float*)d_in[0];
    const float* x = (const float*)d_in[1];
    const int* ei = (const int*)d_in[2];
    const float* We1 = (const float*)d_in[3];
    const float* be1 = (const float*)d_in[4];
    const float* We2 = (const float*)d_in[5];
    const float* be2 = (const float*)d_in[6];
    const float* Wf1 = (const float*)d_in[7];
    const float* bf1 = (const float*)d_in[8];
    const float* Wf2 = (const float*)d_in[9];
    const float* bf2 = (const float*)d_in[10];
    const float* Wout = (const float*)d_in[11];
    const float* bout = (const float*)d_in[12];
    float* out = (float*)d_out;

    int N = in_sizes[0] / 128;
    int E = in_sizes[2] / 2;
    const int* src = ei;
    const int* dst = ei + E;

    char* base = (char*)d_ws;
    size_t off = 0;
    auto take = [&](size_t nbytes) -> char* {
        char* p = base + off;
        off = (off + nbytes + 255) & ~(size_t)255;
        return p;
    };
    int NB = (N + 255) / 256;
    int* cnt = (int*)take((size_t)N * 4);
    int* bsum = (int*)take(1024 * 4);
    int* boff = (int*)take(1024 * 4);
    int* rowp = (int*)take(((size_t)N + 1) * 4);
    float* dinv = (float*)take((size_t)N * 4);
    int* rank = (int*)take((size_t)E * 4);
    int* csrc = (int*)take((size_t)E * 4);
    __half2* hzx = (__half2*)take((size_t)N * 64 * 4);
    float* azx = (float*)take((size_t)N * 128 * 4);

    hipMemsetAsync(cnt, 0, (size_t)N * 4, stream);

    int egrid = (E + 255) / 256;
    k_deg<<<egrid, 256, 0, stream>>>(dst, E, cnt, rank);
    k_scan1<<<NB, 256, 0, stream>>>(cnt, N, bsum);
    k_scan2<<<1, 256, 0, stream>>>(bsum, NB, boff, rowp, N, E);
    k_scan3<<<NB, 256, 0, stream>>>(cnt, boff, N, rowp, dinv);
    k_fill<<<egrid, 256, 0, stream>>>(src, dst, rank, E, rowp, csrc);

    int mmgrid = (N + 63) / 64;
    int agrid = (N + 3) / 4;

    k_mm1<<<mmgrid, 256, 0, stream>>>(z, x, We1, Wf1, hzx, N);
    k_agg_act<<<agrid, 256, 0, stream>>>(rowp, csrc, dinv, hzx, be1, bf1, azx, N);
    k_mm2i<<<mmgrid, 256, 0, stream>>>(azx, We2, Wf2, hzx, N);
    k_agg_final<<<agrid, 256, 0, stream>>>(rowp, csrc, dinv, hzx, be2, bf2, Wout,
                                           bout, out, N);
}

// Round 6
// 190.174 us; speedup vs baseline: 2.4097x; 1.0700x over previous
//
#include <hip/hip_runtime.h>
#include <hip/hip_fp16.h>
#include <math.h>

#define RRELU_SLOPE 0.22916667f  // (1/8 + 1/3)/2 = 11/48

// ---------------------------------------------------------------------------
// CSR build: histogram(+rank) -> scan -> rank-based scatter (no atomic)
// ---------------------------------------------------------------------------

__global__ __launch_bounds__(256) void k_deg(const int* __restrict__ dst, int E,
                                             int* __restrict__ cnt,
                                             int* __restrict__ rank) {
    int e = blockIdx.x * 256 + threadIdx.x;
    if (e < E) rank[e] = atomicAdd(&cnt[dst[e]], 1);
}

__global__ __launch_bounds__(256) void k_scan1(const int* __restrict__ cnt, int N,
                                               int* __restrict__ bsum) {
    int i = blockIdx.x * 256 + threadIdx.x;
    int v = (i < N) ? cnt[i] : 0;
    for (int o = 32; o >= 1; o >>= 1) v += __shfl_xor(v, o, 64);
    __shared__ int ws[4];
    if ((threadIdx.x & 63) == 0) ws[threadIdx.x >> 6] = v;
    __syncthreads();
    if (threadIdx.x == 0) bsum[blockIdx.x] = ws[0] + ws[1] + ws[2] + ws[3];
}

__global__ __launch_bounds__(256) void k_scan2(const int* __restrict__ bsum, int NB,
                                               int* __restrict__ boff,
                                               int* __restrict__ rowp, int N, int E) {
    __shared__ int s[256];
    int t = threadIdx.x;
    int v[4];
    int loc = 0;
    for (int i = 0; i < 4; i++) {
        int idx = t * 4 + i;
        v[i] = (idx < NB) ? bsum[idx] : 0;
        loc += v[i];
    }
    s[t] = loc;
    __syncthreads();
    for (int o = 1; o < 256; o <<= 1) {
        int u = (t >= o) ? s[t - o] : 0;
        __syncthreads();
        s[t] += u;
        __syncthreads();
    }
    int excl = s[t] - loc;
    for (int i = 0; i < 4; i++) {
        int idx = t * 4 + i;
        if (idx < NB) { boff[idx] = excl; excl += v[i]; }
    }
    if (t == 0) rowp[N] = E;
}

__global__ __launch_bounds__(256) void k_scan3(const int* __restrict__ cnt,
                                               const int* __restrict__ boff, int N,
                                               int* __restrict__ rowp,
                                               float* __restrict__ dinv) {
    int i = blockIdx.x * 256 + threadIdx.x;
    int lane = threadIdx.x & 63, wid = threadIdx.x >> 6;
    int v = (i < N) ? cnt[i] : 0;
    int inc = v;
    for (int o = 1; o < 64; o <<= 1) {
        int u = __shfl_up(inc, o, 64);
        if (lane >= o) inc += u;
    }
    __shared__ int wsum[4];
    if (lane == 63) wsum[wid] = inc;
    __syncthreads();
    int wo = 0;
    for (int w = 0; w < wid; w++) wo += wsum[w];
    if (i < N) {
        int excl = inc - v + wo + boff[blockIdx.x];
        rowp[i] = excl;
        dinv[i] = 1.0f / sqrtf((float)v + 1.0f);
    }
}

__global__ __launch_bounds__(256) void k_fill(const int* __restrict__ src,
                                              const int* __restrict__ dst,
                                              const int* __restrict__ rank, int E,
                                              const int* __restrict__ rowp,
                                              int* __restrict__ csrc) {
    int e = blockIdx.x * 256 + threadIdx.x;
    if (e >= E) return;
    int d = dst[e];
    csrc[rowp[d] + rank[e]] = src[e];
}

// ---------------------------------------------------------------------------
// Matmul, one branch per block (blockIdx.y): Hh' = fp16(dinv[r] * (A @ W)).
// Block = 256 threads -> 64 rows x 64 cols, 4x4 register micro-kernel.
// Output planes: Hh + branch*N*64 (fp16).
// ---------------------------------------------------------------------------
template <int K>
__global__ __launch_bounds__(256) void k_mm(const float* __restrict__ A0,
                                            const float* __restrict__ A1,
                                            const float* __restrict__ W0,
                                            const float* __restrict__ W1,
                                            const float* __restrict__ dinv,
                                            __half* __restrict__ Hh, int N) {
    const float* A = blockIdx.y ? A1 : A0;
    const float* W = blockIdx.y ? W1 : W0;
    __half* H = Hh + (size_t)blockIdx.y * N * 64;

    __shared__ float As[64][20];  // 64 rows x 16 k, stride 20 (80B)
    __shared__ float Ws[16][64];  // 16 k x 64 cols

    const int tid = threadIdx.x;
    const int tc = tid & 15, tr = tid >> 4;
    const int row0 = blockIdx.x * 64;
    const int srow = tid >> 2, sk = (tid & 3) * 4;
    const int wk = tid >> 4, wc = (tid & 15) * 4;

    float acc[4][4] = {};

    for (int k0 = 0; k0 < K; k0 += 16) {
        float4 av = make_float4(0.f, 0.f, 0.f, 0.f);
        int gr = row0 + srow;
        if (gr < N) av = *(const float4*)(A + (size_t)gr * K + k0 + sk);
        float4 wv = *(const float4*)(W + (size_t)(k0 + wk) * 64 + wc);
        __syncthreads();
        *(float4*)&As[srow][sk] = av;
        *(float4*)&Ws[wk][wc] = wv;
        __syncthreads();

#pragma unroll
        for (int k = 0; k < 16; k += 4) {
            float4 a4[4], w4[4];
#pragma unroll
            for (int i = 0; i < 4; i++) a4[i] = *(const float4*)&As[tr * 4 + i][k];
#pragma unroll
            for (int kk = 0; kk < 4; kk++) w4[kk] = *(const float4*)&Ws[k + kk][tc * 4];
#pragma unroll
            for (int i = 0; i < 4; i++) {
                const float* ap = (const float*)&a4[i];
#pragma unroll
                for (int kk = 0; kk < 4; kk++) {
                    const float* wp = (const float*)&w4[kk];
                    float a = ap[kk];
                    acc[i][0] = fmaf(a, wp[0], acc[i][0]);
                    acc[i][1] = fmaf(a, wp[1], acc[i][1]);
                    acc[i][2] = fmaf(a, wp[2], acc[i][2]);
                    acc[i][3] = fmaf(a, wp[3], acc[i][3]);
                }
            }
        }
    }

#pragma unroll
    for (int i = 0; i < 4; i++) {
        int r = row0 + tr * 4 + i;
        if (r < N) {
            float dv = dinv[r];
            union { __half2 h2[2]; uint2 u; } pk;
            pk.h2[0] = __floats2half2_rn(acc[i][0] * dv, acc[i][1] * dv);
            pk.h2[1] = __floats2half2_rn(acc[i][2] * dv, acc[i][3] * dv);
            *(uint2*)(H + (size_t)r * 64 + tc * 4) = pk.u;
        }
    }
}

// ---------------------------------------------------------------------------
// Aggregation over pre-scaled fp16 planes. 1 wave/node. Lanes 0-31 cover the
// z plane (half2 j = lane), lanes 32-63 the x plane. Inner loop = pure
// gather+add (dinv folded into H'), 8 edges in flight, 4 chains.
//   result[f] = dinv_i * (sum_c H'[c][f] + H'[i][f]) + b[f]
// ---------------------------------------------------------------------------
#define AGG_EDGE(S, C)                                   \
    {                                                    \
        float2 h_ = __half22float2(Hp[(size_t)(C) * 32]);\
        S.x += h_.x;                                     \
        S.y += h_.y;                                     \
    }

__global__ __launch_bounds__(256) void k_agg_act(
    const int* __restrict__ rowp, const int* __restrict__ csrc,
    const float* __restrict__ dinv, const __half2* __restrict__ H2, int N,
    const float* __restrict__ bz, const float* __restrict__ bx,
    float* __restrict__ az, float* __restrict__ ax) {
    int wid = threadIdx.x >> 6, lane = threadIdx.x & 63;
    int i = blockIdx.x * 4 + wid;
    if (i >= N) return;
    int j = lane & 31;
    const __half2* Hp = H2 + (size_t)(lane >> 5) * N * 32 + j;
    int beg = rowp[i], end = rowp[i + 1];
    float2 s0 = {0.f, 0.f}, s1 = {0.f, 0.f}, s2 = {0.f, 0.f}, s3 = {0.f, 0.f};
    int p = beg;
    while (p < end && (p & 3)) { int c = csrc[p++]; AGG_EDGE(s0, c); }
    for (; p + 8 <= end; p += 8) {
        int4 ca = *(const int4*)(csrc + p);
        int4 cb = *(const int4*)(csrc + p + 4);
        AGG_EDGE(s0, ca.x);
        AGG_EDGE(s1, ca.y);
        AGG_EDGE(s2, ca.z);
        AGG_EDGE(s3, ca.w);
        AGG_EDGE(s0, cb.x);
        AGG_EDGE(s1, cb.y);
        AGG_EDGE(s2, cb.z);
        AGG_EDGE(s3, cb.w);
    }
    if (p + 4 <= end) {
        int4 ca = *(const int4*)(csrc + p);
        AGG_EDGE(s0, ca.x);
        AGG_EDGE(s1, ca.y);
        AGG_EDGE(s2, ca.z);
        AGG_EDGE(s3, ca.w);
        p += 4;
    }
    while (p < end) { int c = csrc[p++]; AGG_EDGE(s0, c); }

    float2 hs = __half22float2(Hp[(size_t)i * 32]);
    float sumx = ((s0.x + s1.x) + (s2.x + s3.x)) + hs.x;
    float sumy = ((s0.y + s1.y) + (s2.y + s3.y)) + hs.y;
    float dvi = dinv[i];
    const float* bb = (lane >= 32) ? bx : bz;
    float2 b = *(const float2*)(bb + 2 * j);
    float f0 = fmaf(dvi, sumx, b.x);
    float f1 = fmaf(dvi, sumy, b.y);
    f0 = f0 >= 0.f ? f0 : f0 * RRELU_SLOPE;
    f1 = f1 >= 0.f ? f1 : f1 * RRELU_SLOPE;
    float* ap = (lane >= 32) ? ax : az;
    *(float2*)(ap + (size_t)i * 64 + 2 * j) = make_float2(f0, f1);
}

__global__ __launch_bounds__(256) void k_agg_final(
    const int* __restrict__ rowp, const int* __restrict__ csrc,
    const float* __restrict__ dinv, const __half2* __restrict__ H2, int N,
    const float* __restrict__ bz, const float* __restrict__ bx,
    const float* __restrict__ Wout, const float* __restrict__ bout,
    float* __restrict__ out) {
    int wid = threadIdx.x >> 6, lane = threadIdx.x & 63;
    int i = blockIdx.x * 4 + wid;
    if (i >= N) return;
    int j = lane & 31;
    const __half2* Hp = H2 + (size_t)(lane >> 5) * N * 32 + j;
    int beg = rowp[i], end = rowp[i + 1];
    float2 s0 = {0.f, 0.f}, s1 = {0.f, 0.f}, s2 = {0.f, 0.f}, s3 = {0.f, 0.f};
    int p = beg;
    while (p < end && (p & 3)) { int c = csrc[p++]; AGG_EDGE(s0, c); }
    for (; p + 8 <= end; p += 8) {
        int4 ca = *(const int4*)(csrc + p);
        int4 cb = *(const int4*)(csrc + p + 4);
        AGG_EDGE(s0, ca.x);
        AGG_EDGE(s1, ca.y);
        AGG_EDGE(s2, ca.z);
        AGG_EDGE(s3, ca.w);
        AGG_EDGE(s0, cb.x);
        AGG_EDGE(s1, cb.y);
        AGG_EDGE(s2, cb.z);
        AGG_EDGE(s3, cb.w);
    }
    if (p + 4 <= end) {
        int4 ca = *(const int4*)(csrc + p);
        AGG_EDGE(s0, ca.x);
        AGG_EDGE(s1, ca.y);
        AGG_EDGE(s2, ca.z);
        AGG_EDGE(s3, ca.w);
        p += 4;
    }
    while (p < end) { int c = csrc[p++]; AGG_EDGE(s0, c); }

    float2 hs = __half22float2(Hp[(size_t)i * 32]);
    float sumx = ((s0.x + s1.x) + (s2.x + s3.x)) + hs.x;
    float sumy = ((s0.y + s1.y) + (s2.y + s3.y)) + hs.y;
    float dvi = dinv[i];
    const float* bb = (lane >= 32) ? bx : bz;
    float2 b = *(const float2*)(bb + 2 * j);
    float t0 = tanhf(fmaf(dvi, sumx, b.x));
    float t1 = tanhf(fmaf(dvi, sumy, b.y));
    // pair z-lane with x-lane (lane ^ 32) and dot with Wout
    float p0 = __shfl_xor(t0, 32, 64);
    float p1 = __shfl_xor(t1, 32, 64);
    float2 w = *(const float2*)(Wout + 2 * j);
    float prod = t0 * p0 * w.x + t1 * p1 * w.y;
    for (int o = 16; o >= 1; o >>= 1) prod += __shfl_xor(prod, o, 64);
    if (lane == 0) out[i] = prod + bout[0];
}

// ---------------------------------------------------------------------------

extern "C" void kernel_launch(void* const* d_in, const int* in_sizes, int n_in,
                              void* d_out, int out_size, void* d_ws, size_t ws_size,
                              hipStream_t stream) {
    const float* z = (const float*)d_in[0];
    const float* x = (const float*)d_in[1];
    const int* ei = (const int*)d_in[2];
    const float* We1 = (const float*)d_in[3];
    const float* be1 = (const float*)d_in[4];
    const float* We2 = (const float*)d_in[5];
    const float* be2 = (const float*)d_in[6];
    const float* Wf1 = (const float*)d_in[7];
    const float* bf1 = (const float*)d_in[8];
    const float* Wf2 = (const float*)d_in[9];
    const float* bf2 = (const float*)d_in[10];
    const float* Wout = (const float*)d_in[11];
    const float* bout = (const float*)d_in[12];
    float* out = (float*)d_out;

    int N = in_sizes[0] / 128;
    int E = in_sizes[2] / 2;
    const int* src = ei;
    const int* dst = ei + E;

    char* base = (char*)d_ws;
    size_t off = 0;
    auto take = [&](size_t nbytes) -> char* {
        char* p = base + off;
        off = (off + nbytes + 255) & ~(size_t)255;
        return p;
    };
    int NB = (N + 255) / 256;
    int* cnt = (int*)take((size_t)N * 4);
    int* bsum = (int*)take(1024 * 4);
    int* boff = (int*)take(1024 * 4);
    int* rowp = (int*)take(((size_t)N + 1) * 4);
    float* dinv = (float*)take((size_t)N * 4);
    int* rank = (int*)take((size_t)E * 4);
    int* csrc = (int*)take((size_t)E * 4);
    __half* Hh = (__half*)take((size_t)N * 64 * 2 * 2);  // 2 planes fp16
    float* az = (float*)take((size_t)N * 64 * 4);
    float* ax = (float*)take((size_t)N * 64 * 4);

    hipMemsetAsync(cnt, 0, (size_t)N * 4, stream);

    int egrid = (E + 255) / 256;
    k_deg<<<egrid, 256, 0, stream>>>(dst, E, cnt, rank);
    k_scan1<<<NB, 256, 0, stream>>>(cnt, N, bsum);
    k_scan2<<<1, 256, 0, stream>>>(bsum, NB, boff, rowp, N, E);
    k_scan3<<<NB, 256, 0, stream>>>(cnt, boff, N, rowp, dinv);
    k_fill<<<egrid, 256, 0, stream>>>(src, dst, rank, E, rowp, csrc);

    dim3 mmgrid((N + 63) / 64, 2);
    int agrid = (N + 3) / 4;
    const __half2* H2 = (const __half2*)Hh;

    k_mm<128><<<mmgrid, 256, 0, stream>>>(z, x, We1, Wf1, dinv, Hh, N);
    k_agg_act<<<agrid, 256, 0, stream>>>(rowp, csrc, dinv, H2, N, be1, bf1, az, ax);
    k_mm<64><<<mmgrid, 256, 0, stream>>>(az, ax, We2, Wf2, dinv, Hh, N);
    k_agg_final<<<agrid, 256, 0, stream>>>(rowp, csrc, dinv, H2, N, be2, bf2, Wout,
                                           bout, out);
}

// Round 7
// 189.463 us; speedup vs baseline: 2.4187x; 1.0038x over previous
//
#include <hip/hip_runtime.h>
#include <hip/hip_fp16.h>
#include <math.h>

#define RRELU_SLOPE 0.22916667f  // (1/8 + 1/3)/2 = 11/48

// ---------------------------------------------------------------------------
// CSR build: zero -> histogram(+rank) -> scan -> rank-based scatter
// ---------------------------------------------------------------------------

__global__ __launch_bounds__(256) void k_zero(int* __restrict__ cnt, int N) {
    int i = blockIdx.x * 256 + threadIdx.x;
    if (i < N) cnt[i] = 0;
}

__global__ __launch_bounds__(256) void k_deg(const int* __restrict__ dst, int E,
                                             int* __restrict__ cnt,
                                             int* __restrict__ rank) {
    int e = blockIdx.x * 256 + threadIdx.x;
    if (e < E) rank[e] = atomicAdd(&cnt[dst[e]], 1);
}

__global__ __launch_bounds__(256) void k_scan1(const int* __restrict__ cnt, int N,
                                               int* __restrict__ bsum) {
    int i = blockIdx.x * 256 + threadIdx.x;
    int v = (i < N) ? cnt[i] : 0;
    for (int o = 32; o >= 1; o >>= 1) v += __shfl_xor(v, o, 64);
    __shared__ int ws[4];
    if ((threadIdx.x & 63) == 0) ws[threadIdx.x >> 6] = v;
    __syncthreads();
    if (threadIdx.x == 0) bsum[blockIdx.x] = ws[0] + ws[1] + ws[2] + ws[3];
}

__global__ __launch_bounds__(256) void k_scan2(const int* __restrict__ bsum, int NB,
                                               int* __restrict__ boff,
                                               int* __restrict__ rowp, int N, int E) {
    __shared__ int s[256];
    int t = threadIdx.x;
    int v[4];
    int loc = 0;
    for (int i = 0; i < 4; i++) {
        int idx = t * 4 + i;
        v[i] = (idx < NB) ? bsum[idx] : 0;
        loc += v[i];
    }
    s[t] = loc;
    __syncthreads();
    for (int o = 1; o < 256; o <<= 1) {
        int u = (t >= o) ? s[t - o] : 0;
        __syncthreads();
        s[t] += u;
        __syncthreads();
    }
    int excl = s[t] - loc;
    for (int i = 0; i < 4; i++) {
        int idx = t * 4 + i;
        if (idx < NB) { boff[idx] = excl; excl += v[i]; }
    }
    if (t == 0) rowp[N] = E;
}

__global__ __launch_bounds__(256) void k_scan3(const int* __restrict__ cnt,
                                               const int* __restrict__ boff, int N,
                                               int* __restrict__ rowp,
                                               float* __restrict__ dinv) {
    int i = blockIdx.x * 256 + threadIdx.x;
    int lane = threadIdx.x & 63, wid = threadIdx.x >> 6;
    int v = (i < N) ? cnt[i] : 0;
    int inc = v;
    for (int o = 1; o < 64; o <<= 1) {
        int u = __shfl_up(inc, o, 64);
        if (lane >= o) inc += u;
    }
    __shared__ int wsum[4];
    if (lane == 63) wsum[wid] = inc;
    __syncthreads();
    int wo = 0;
    for (int w = 0; w < wid; w++) wo += wsum[w];
    if (i < N) {
        int excl = inc - v + wo + boff[blockIdx.x];
        rowp[i] = excl;
        dinv[i] = 1.0f / sqrtf((float)v + 1.0f);
    }
}

__global__ __launch_bounds__(256) void k_fill(const int* __restrict__ src,
                                              const int* __restrict__ dst,
                                              const int* __restrict__ rank, int E,
                                              const int* __restrict__ rowp,
                                              int* __restrict__ csrc) {
    int e = blockIdx.x * 256 + threadIdx.x;
    if (e >= E) return;
    int d = dst[e];
    csrc[rowp[d] + rank[e]] = src[e];
}

// ---------------------------------------------------------------------------
// Matmul, one branch per block (blockIdx.y): Hh' = fp16(dinv[r] * (A @ W)).
// Block = 256 threads -> 64 rows x 64 cols, 4x4 register micro-kernel.
// Output planes: Hh + branch*N*64 (fp16).
// ---------------------------------------------------------------------------
template <int K>
__global__ __launch_bounds__(256) void k_mm(const float* __restrict__ A0,
                                            const float* __restrict__ A1,
                                            const float* __restrict__ W0,
                                            const float* __restrict__ W1,
                                            const float* __restrict__ dinv,
                                            __half* __restrict__ Hh, int N) {
    const float* A = blockIdx.y ? A1 : A0;
    const float* W = blockIdx.y ? W1 : W0;
    __half* H = Hh + (size_t)blockIdx.y * N * 64;

    __shared__ float As[64][20];  // 64 rows x 16 k, stride 20 (80B)
    __shared__ float Ws[16][64];  // 16 k x 64 cols

    const int tid = threadIdx.x;
    const int tc = tid & 15, tr = tid >> 4;
    const int row0 = blockIdx.x * 64;
    const int srow = tid >> 2, sk = (tid & 3) * 4;
    const int wk = tid >> 4, wc = (tid & 15) * 4;

    float acc[4][4] = {};

    for (int k0 = 0; k0 < K; k0 += 16) {
        float4 av = make_float4(0.f, 0.f, 0.f, 0.f);
        int gr = row0 + srow;
        if (gr < N) av = *(const float4*)(A + (size_t)gr * K + k0 + sk);
        float4 wv = *(const float4*)(W + (size_t)(k0 + wk) * 64 + wc);
        __syncthreads();
        *(float4*)&As[srow][sk] = av;
        *(float4*)&Ws[wk][wc] = wv;
        __syncthreads();

#pragma unroll
        for (int k = 0; k < 16; k += 4) {
            float4 a4[4], w4[4];
#pragma unroll
            for (int i = 0; i < 4; i++) a4[i] = *(const float4*)&As[tr * 4 + i][k];
#pragma unroll
            for (int kk = 0; kk < 4; kk++) w4[kk] = *(const float4*)&Ws[k + kk][tc * 4];
#pragma unroll
            for (int i = 0; i < 4; i++) {
                const float* ap = (const float*)&a4[i];
#pragma unroll
                for (int kk = 0; kk < 4; kk++) {
                    const float* wp = (const float*)&w4[kk];
                    float a = ap[kk];
                    acc[i][0] = fmaf(a, wp[0], acc[i][0]);
                    acc[i][1] = fmaf(a, wp[1], acc[i][1]);
                    acc[i][2] = fmaf(a, wp[2], acc[i][2]);
                    acc[i][3] = fmaf(a, wp[3], acc[i][3]);
                }
            }
        }
    }

#pragma unroll
    for (int i = 0; i < 4; i++) {
        int r = row0 + tr * 4 + i;
        if (r < N) {
            float dv = dinv[r];
            union { __half2 h2[2]; uint2 u; } pk;
            pk.h2[0] = __floats2half2_rn(acc[i][0] * dv, acc[i][1] * dv);
            pk.h2[1] = __floats2half2_rn(acc[i][2] * dv, acc[i][3] * dv);
            *(uint2*)(H + (size_t)r * 64 + tc * 4) = pk.u;
        }
    }
}

// ---------------------------------------------------------------------------
// Aggregation over pre-scaled fp16 planes. 1 wave/node. Lanes 0-31 cover the
// z plane (half2 j = lane), lanes 32-63 the x plane. Inner loop = pure
// gather+add (dinv folded into H'), 8 edges in flight, 4 chains.
//   result[f] = dinv_i * (sum_c H'[c][f] + H'[i][f]) + b[f]
// ---------------------------------------------------------------------------
#define AGG_EDGE(S, C)                                   \
    {                                                    \
        float2 h_ = __half22float2(Hp[(size_t)(C) * 32]);\
        S.x += h_.x;                                     \
        S.y += h_.y;                                     \
    }

__global__ __launch_bounds__(256) void k_agg_act(
    const int* __restrict__ rowp, const int* __restrict__ csrc,
    const float* __restrict__ dinv, const __half2* __restrict__ H2, int N,
    const float* __restrict__ bz, const float* __restrict__ bx,
    float* __restrict__ az, float* __restrict__ ax) {
    int wid = threadIdx.x >> 6, lane = threadIdx.x & 63;
    int i = blockIdx.x * 4 + wid;
    if (i >= N) return;
    int j = lane & 31;
    const __half2* Hp = H2 + (size_t)(lane >> 5) * N * 32 + j;
    int beg = rowp[i], end = rowp[i + 1];
    float2 s0 = {0.f, 0.f}, s1 = {0.f, 0.f}, s2 = {0.f, 0.f}, s3 = {0.f, 0.f};
    int p = beg;
    while (p < end && (p & 3)) { int c = csrc[p++]; AGG_EDGE(s0, c); }
    for (; p + 8 <= end; p += 8) {
        int4 ca = *(const int4*)(csrc + p);
        int4 cb = *(const int4*)(csrc + p + 4);
        AGG_EDGE(s0, ca.x);
        AGG_EDGE(s1, ca.y);
        AGG_EDGE(s2, ca.z);
        AGG_EDGE(s3, ca.w);
        AGG_EDGE(s0, cb.x);
        AGG_EDGE(s1, cb.y);
        AGG_EDGE(s2, cb.z);
        AGG_EDGE(s3, cb.w);
    }
    if (p + 4 <= end) {
        int4 ca = *(const int4*)(csrc + p);
        AGG_EDGE(s0, ca.x);
        AGG_EDGE(s1, ca.y);
        AGG_EDGE(s2, ca.z);
        AGG_EDGE(s3, ca.w);
        p += 4;
    }
    while (p < end) { int c = csrc[p++]; AGG_EDGE(s0, c); }

    float2 hs = __half22float2(Hp[(size_t)i * 32]);
    float sumx = ((s0.x + s1.x) + (s2.x + s3.x)) + hs.x;
    float sumy = ((s0.y + s1.y) + (s2.y + s3.y)) + hs.y;
    float dvi = dinv[i];
    const float* bb = (lane >= 32) ? bx : bz;
    float2 b = *(const float2*)(bb + 2 * j);
    float f0 = fmaf(dvi, sumx, b.x);
    float f1 = fmaf(dvi, sumy, b.y);
    f0 = f0 >= 0.f ? f0 : f0 * RRELU_SLOPE;
    f1 = f1 >= 0.f ? f1 : f1 * RRELU_SLOPE;
    float* ap = (lane >= 32) ? ax : az;
    *(float2*)(ap + (size_t)i * 64 + 2 * j) = make_float2(f0, f1);
}

__global__ __launch_bounds__(256) void k_agg_final(
    const int* __restrict__ rowp, const int* __restrict__ csrc,
    const float* __restrict__ dinv, const __half2* __restrict__ H2, int N,
    const float* __restrict__ bz, const float* __restrict__ bx,
    const float* __restrict__ Wout, const float* __restrict__ bout,
    float* __restrict__ out) {
    int wid = threadIdx.x >> 6, lane = threadIdx.x & 63;
    int i = blockIdx.x * 4 + wid;
    if (i >= N) return;
    int j = lane & 31;
    const __half2* Hp = H2 + (size_t)(lane >> 5) * N * 32 + j;
    int beg = rowp[i], end = rowp[i + 1];
    float2 s0 = {0.f, 0.f}, s1 = {0.f, 0.f}, s2 = {0.f, 0.f}, s3 = {0.f, 0.f};
    int p = beg;
    while (p < end && (p & 3)) { int c = csrc[p++]; AGG_EDGE(s0, c); }
    for (; p + 8 <= end; p += 8) {
        int4 ca = *(const int4*)(csrc + p);
        int4 cb = *(const int4*)(csrc + p + 4);
        AGG_EDGE(s0, ca.x);
        AGG_EDGE(s1, ca.y);
        AGG_EDGE(s2, ca.z);
        AGG_EDGE(s3, ca.w);
        AGG_EDGE(s0, cb.x);
        AGG_EDGE(s1, cb.y);
        AGG_EDGE(s2, cb.z);
        AGG_EDGE(s3, cb.w);
    }
    if (p + 4 <= end) {
        int4 ca = *(const int4*)(csrc + p);
        AGG_EDGE(s0, ca.x);
        AGG_EDGE(s1, ca.y);
        AGG_EDGE(s2, ca.z);
        AGG_EDGE(s3, ca.w);
        p += 4;
    }
    while (p < end) { int c = csrc[p++]; AGG_EDGE(s0, c); }

    float2 hs = __half22float2(Hp[(size_t)i * 32]);
    float sumx = ((s0.x + s1.x) + (s2.x + s3.x)) + hs.x;
    float sumy = ((s0.y + s1.y) + (s2.y + s3.y)) + hs.y;
    float dvi = dinv[i];
    const float* bb = (lane >= 32) ? bx : bz;
    float2 b = *(const float2*)(bb + 2 * j);
    float t0 = tanhf(fmaf(dvi, sumx, b.x));
    float t1 = tanhf(fmaf(dvi, sumy, b.y));
    // pair z-lane with x-lane (lane ^ 32) and dot with Wout
    float p0 = __shfl_xor(t0, 32, 64);
    float p1 = __shfl_xor(t1, 32, 64);
    float2 w = *(const float2*)(Wout + 2 * j);
    float prod = t0 * p0 * w.x + t1 * p1 * w.y;
    for (int o = 16; o >= 1; o >>= 1) prod += __shfl_xor(prod, o, 64);
    if (lane == 0) out[i] = prod + bout[0];
}

// ---------------------------------------------------------------------------

extern "C" void kernel_launch(void* const* d_in, const int* in_sizes, int n_in,
                              void* d_out, int out_size, void* d_ws, size_t ws_size,
                              hipStream_t stream) {
    const float* z = (const float*)d_in[0];
    const float* x = (const float*)d_in[1];
    const int* ei = (const int*)d_in[2];
    const float* We1 = (const float*)d_in[3];
    const float* be1 = (const float*)d_in[4];
    const float* We2 = (const float*)d_in[5];
    const float* be2 = (const float*)d_in[6];
    const float* Wf1 = (const float*)d_in[7];
    const float* bf1 = (const float*)d_in[8];
    const float* Wf2 = (const float*)d_in[9];
    const float* bf2 = (const float*)d_in[10];
    const float* Wout = (const float*)d_in[11];
    const float* bout = (const float*)d_in[12];
    float* out = (float*)d_out;

    int N = in_sizes[0] / 128;
    int E = in_sizes[2] / 2;
    const int* src = ei;
    const int* dst = ei + E;

    char* base = (char*)d_ws;
    size_t off = 0;
    auto take = [&](size_t nbytes) -> char* {
        char* p = base + off;
        off = (off + nbytes + 255) & ~(size_t)255;
        return p;
    };
    int NB = (N + 255) / 256;
    int* cnt = (int*)take((size_t)N * 4);
    int* bsum = (int*)take(1024 * 4);
    int* boff = (int*)take(1024 * 4);
    int* rowp = (int*)take(((size_t)N + 1) * 4);
    float* dinv = (float*)take((size_t)N * 4);
    int* rank = (int*)take((size_t)E * 4);
    int* csrc = (int*)take((size_t)E * 4);
    __half* Hh = (__half*)take((size_t)N * 64 * 2 * 2);  // 2 planes fp16
    float* az = (float*)take((size_t)N * 64 * 4);
    float* ax = (float*)take((size_t)N * 64 * 4);

    int egrid = (E + 255) / 256;
    k_zero<<<NB, 256, 0, stream>>>(cnt, N);
    k_deg<<<egrid, 256, 0, stream>>>(dst, E, cnt, rank);
    k_scan1<<<NB, 256, 0, stream>>>(cnt, N, bsum);
    k_scan2<<<1, 256, 0, stream>>>(bsum, NB, boff, rowp, N, E);
    k_scan3<<<NB, 256, 0, stream>>>(cnt, boff, N, rowp, dinv);
    k_fill<<<egrid, 256, 0, stream>>>(src, dst, rank, E, rowp, csrc);

    dim3 mmgrid((N + 63) / 64, 2);
    int agrid = (N + 3) / 4;
    const __half2* H2 = (const __half2*)Hh;

    k_mm<128><<<mmgrid, 256, 0, stream>>>(z, x, We1, Wf1, dinv, Hh, N);
    k_agg_act<<<agrid, 256, 0, stream>>>(rowp, csrc, dinv, H2, N, be1, bf1, az, ax);
    k_mm<64><<<mmgrid, 256, 0, stream>>>(az, ax, We2, Wf2, dinv, Hh, N);
    k_agg_final<<<agrid, 256, 0, stream>>>(rowp, csrc, dinv, H2, N, be2, bf2, Wout,
                                           bout, out);
}